// Round 6
// baseline (1295.348 us; speedup 1.0000x reference)
//
#include <hip/hip_runtime.h>
#include <hip/hip_bf16.h>

typedef __bf16 bf16x8 __attribute__((ext_vector_type(8)));
typedef float f32x4 __attribute__((ext_vector_type(4)));

#define HIDDEN 4096
#define NH 32
#define HD 128
#define SEQ 2048
#define BATCH 2
#define MTOT 4096           // BATCH*SEQ
#define QKV 12288

// ---- async global->LDS, 16B per lane; LDS dest = wave-uniform base + lane*16 ----
__device__ __forceinline__ void async16(const void* g, void* l) {
    __builtin_amdgcn_global_load_lds(
        (const __attribute__((address_space(1))) void*)(uintptr_t)g,
        (__attribute__((address_space(3))) void*)(uint32_t)(uintptr_t)l,
        16, 0, 0);
}

// Load 8 source elements and return them as 8 packed bf16 (one uint4).
__device__ __forceinline__ uint4 ld8(const __hip_bfloat16* p) { return *(const uint4*)p; }
__device__ __forceinline__ uint4 ld8(const float* p) {
    float4 a = *(const float4*)p;
    float4 b = *(const float4*)(p + 4);
    __hip_bfloat16 t[8];
    t[0] = __float2bfloat16(a.x); t[1] = __float2bfloat16(a.y);
    t[2] = __float2bfloat16(a.z); t[3] = __float2bfloat16(a.w);
    t[4] = __float2bfloat16(b.x); t[5] = __float2bfloat16(b.y);
    t[6] = __float2bfloat16(b.z); t[7] = __float2bfloat16(b.w);
    return *(uint4*)t;
}

__device__ __forceinline__ void stc(__hip_bfloat16* C, size_t i, float v) { C[i] = __float2bfloat16(v); }
__device__ __forceinline__ void stc(float* C, size_t i, float v) { C[i] = v; }

// fp32 -> bf16 bulk convert, 8 elems/thread.
__global__ __launch_bounds__(256) void cvt_bf16(const float* __restrict__ src,
                                                __hip_bfloat16* __restrict__ dst, int n8) {
    int i = blockIdx.x * 256 + threadIdx.x;
    if (i < n8) *(uint4*)&dst[(size_t)i * 8] = ld8(&src[(size_t)i * 8]);
}

// 256x256-tile GEMM, BK=32, 4-slot LDS ring, counted vmcnt (T3+T4+T5),
// FRAGMENT-ORDERED LDS. C[M,N] = A[M,K] @ Bt[N,K]^T, bf16 in, fp32 acc.
// 8 waves (2M x 4N), per-wave output 128x64 (acc[8][4]).
//
// Fragment-order staging: each async16 stages one 1-KiB "fragment block"
// (16 rows x 32 cols) with the GLOBAL source permuted per-lane so that the
// linear LDS write (dest = base + lane*16) lands data in exactly the order
// the MFMA fragment read wants: lane L holds row (L&15), k-chunk (L>>4).
// Reads are then ds_read_b128 at LDS addr = block_base + lane*16 --
// consecutive 16B per lane, structurally zero bank conflicts (same pattern
// as the conflict-free linear write). Global footprint per instruction is
// unchanged (16 rows x 64 B), so coalescing is identical.
template <typename TC>
__global__ __launch_bounds__(512) void gemm_256(const __hip_bfloat16* __restrict__ A,
                                                const __hip_bfloat16* __restrict__ Bt,
                                                TC* __restrict__ C,
                                                int M, int N, int K, int lda) {
    // [slot][fragment block][512 bf16 = 1 KiB]; block j of A holds rows j*16..j*16+15.
    __shared__ __align__(16) __hip_bfloat16 As[4][16][512];   // 64 KiB
    __shared__ __align__(16) __hip_bfloat16 Bs[4][16][512];   // 64 KiB
    const int bn = blockIdx.x * 256, bm = blockIdx.y * 256;
    const int tid = threadIdx.x, wave = tid >> 6, lane = tid & 63;
    const int wm = wave >> 2, wn = wave & 3;      // 2 x 4 wave grid
    const int row16 = lane & 15, quad = lane >> 4;
    // fragment-order source: lane L -> row (L&15), k-chunk (L>>4)*8 elems
    const __hip_bfloat16* Ab = A + (size_t)(bm + wave * 16 + row16) * lda + quad * 8;
    const __hip_bfloat16* Bb = Bt + (size_t)(bn + wave * 16 + row16) * K + quad * 8;
    const int NT = K >> 5;

    f32x4 acc[8][4] = {};

    auto stage = [&](int t) {
        const int s = t & 3;
        const int kt = t << 5;
        async16(Ab + kt,                     &As[s][wave][0]);       // rows wave*16..
        async16(Ab + (size_t)128 * lda + kt, &As[s][wave + 8][0]);   // rows +128
        async16(Bb + kt,                     &Bs[s][wave][0]);
        async16(Bb + (size_t)128 * K + kt,   &Bs[s][wave + 8][0]);
    };

    stage(0); stage(1); stage(2);       // 12 loads in flight

    for (int t = 0; t < NT; ++t) {
        const int s = t & 3;
        const int rem = NT - 1 - t;
        // Own-wave loads for tile t must have landed; allow 2 tiles (8 loads)
        // to remain outstanding. Epilogue drains 8 -> 4 -> 0.
        if (rem >= 2)      asm volatile("s_waitcnt vmcnt(8)" ::: "memory");
        else if (rem == 1) asm volatile("s_waitcnt vmcnt(4)" ::: "memory");
        else               asm volatile("s_waitcnt vmcnt(0)" ::: "memory");
        __builtin_amdgcn_s_barrier();
        __builtin_amdgcn_sched_barrier(0);
        if (t + 3 < NT) stage(t + 3);
        bf16x8 af[8], bf[4];
#pragma unroll
        for (int i = 0; i < 8; ++i)
            af[i] = *(const bf16x8*)&As[s][wm * 8 + i][lane * 8];
#pragma unroll
        for (int j = 0; j < 4; ++j)
            bf[j] = *(const bf16x8*)&Bs[s][wn * 4 + j][lane * 8];
        __builtin_amdgcn_s_setprio(1);
#pragma unroll
        for (int i = 0; i < 8; ++i)
#pragma unroll
            for (int j = 0; j < 4; ++j)
                acc[i][j] = __builtin_amdgcn_mfma_f32_16x16x32_bf16(af[i], bf[j], acc[i][j], 0, 0, 0);
        __builtin_amdgcn_s_setprio(0);
    }

    const int col0 = bn + wn * 64 + row16;
    const int row0 = bm + wm * 128 + quad * 4;
#pragma unroll
    for (int i = 0; i < 8; ++i)
#pragma unroll
        for (int j = 0; j < 4; ++j)
#pragma unroll
            for (int rg = 0; rg < 4; ++rg)
                stc(C, (size_t)(row0 + i * 16 + rg) * N + col0 + j * 16, acc[i][j][rg]);
}

// Fallback GEMM (fp32 or bf16 inputs via ld8 staging). Used when ws is small.
template <typename TA, typename TB, typename TC>
__global__ __launch_bounds__(256) void gemm_bt(const TA* __restrict__ A,
                                               const TB* __restrict__ Bt,
                                               TC* __restrict__ C,
                                               int M, int N, int K, int lda) {
    __shared__ __align__(16) __hip_bfloat16 As[128][32];
    __shared__ __align__(16) __hip_bfloat16 Bs[128][32];
    const int bn = blockIdx.x * 128, bm = blockIdx.y * 128;
    const int tid = threadIdx.x, wave = tid >> 6, lane = tid & 63;
    const int wm = (wave >> 1) * 64, wn = (wave & 1) * 64;
    const int row16 = lane & 15, quad = lane >> 4;
    const int arow = tid >> 2;
    const int acol = (tid & 3) * 8;

    f32x4 acc[4][4] = {};

    for (int kt = 0; kt < K; kt += 32) {
        __syncthreads();
#pragma unroll
        for (int it = 0; it < 2; ++it) {
            int r = arow + it * 64;
            *(uint4*)&As[r][acol] = ld8(&A[(size_t)(bm + r) * lda + kt + acol]);
            *(uint4*)&Bs[r][acol] = ld8(&Bt[(size_t)(bn + r) * K + kt + acol]);
        }
        __syncthreads();
        bf16x8 af[4], bf[4];
#pragma unroll
        for (int i = 0; i < 4; ++i) af[i] = *(const bf16x8*)&As[wm + i * 16 + row16][quad * 8];
#pragma unroll
        for (int j = 0; j < 4; ++j) bf[j] = *(const bf16x8*)&Bs[wn + j * 16 + row16][quad * 8];
#pragma unroll
        for (int i = 0; i < 4; ++i)
#pragma unroll
            for (int j = 0; j < 4; ++j)
                acc[i][j] = __builtin_amdgcn_mfma_f32_16x16x32_bf16(af[i], bf[j], acc[i][j], 0, 0, 0);
    }
    const int col0 = bn + wn + row16;
    const int row0 = bm + wm + quad * 4;
#pragma unroll
    for (int i = 0; i < 4; ++i)
#pragma unroll
        for (int j = 0; j < 4; ++j)
#pragma unroll
            for (int rg = 0; rg < 4; ++rg)
                stc(C, (size_t)(row0 + i * 16 + rg) * N + col0 + j * 16, acc[i][j][rg]);
}

// In-place RoPE on the Q and K thirds of proj[MTOT][QKV]. position = row % SEQ.
// Q rows additionally pre-scaled by 1/sqrt(HD) so attn skips the score scaling.
__global__ __launch_bounds__(256) void rope_kernel(__hip_bfloat16* __restrict__ proj) {
    int t = blockIdx.x * 256 + threadIdx.x;
    int j = t & 63;
    int head = (t >> 6) & 31;
    int mat = (t >> 11) & 1;
    int row = t >> 12;
    int pos = row & (SEQ - 1);
    float invf = __expf(-(float)j * 0.14391156514261f);   // 10000^(-j/64)
    float ang = (float)pos * invf;
    float rev = ang * 0.15915494309189535f;               // range-reduce for v_sin/v_cos
    rev -= floorf(rev);
    float arad = rev * 6.283185307179586f;
    float sn = __sinf(arad);
    float cs = __cosf(arad);
    if (mat == 0) {                     // Q third: fold in 1/sqrt(128)
        sn *= 0.08838834764831845f;
        cs *= 0.08838834764831845f;
    }
    size_t base = (size_t)row * QKV + mat * HIDDEN + head * HD + j;
    float x1 = __bfloat162float(proj[base]);
    float x2 = __bfloat162float(proj[base + 64]);
    proj[base]      = __float2bfloat16(x1 * cs - x2 * sn);
    proj[base + 64] = __float2bfloat16(x2 * cs + x1 * sn);
}

// One-shot V transpose: proj V-third [b][s][h*128+d] -> vtg[(b*32+h)][d][s].
__global__ __launch_bounds__(256) void transpose_v(const __hip_bfloat16* __restrict__ proj,
                                                   __hip_bfloat16* __restrict__ vtg) {
    __shared__ __hip_bfloat16 Ls[64][132];
    const int st = blockIdx.x, bh = blockIdx.y;
    const int b = bh >> 5, h = bh & 31;
    const int s0 = st << 6;
    const int tid = threadIdx.x;
    const __hip_bfloat16* vb = proj + (size_t)b * SEQ * QKV + 2 * HIDDEN + h * HD;
    for (int i = tid; i < 1024; i += 256) {
        int r = i >> 4, c = (i & 15) << 3;
        uint4 raw = *(const uint4*)&vb[(size_t)(s0 + r) * QKV + c];
        *(uint2*)&Ls[r][c]     = make_uint2(raw.x, raw.y);
        *(uint2*)&Ls[r][c + 4] = make_uint2(raw.z, raw.w);
    }
    __syncthreads();
    __hip_bfloat16* ob = vtg + (size_t)bh * HD * SEQ + s0;
    for (int t = tid; t < 1024; t += 256) {
        int d = t >> 3, sc = (t & 7) << 3;
        __hip_bfloat16 tmp[8];
#pragma unroll
        for (int x = 0; x < 8; ++x) tmp[x] = Ls[sc + x][d];
        *(uint4*)&ob[(size_t)d * SEQ + sc] = *(uint4*)tmp;
    }
}

// MFMA flash attention. Block = 128 q-rows x (b,h); 4 waves x 32 q-rows each.
// Requires gridDim.x == SEQ/128 == 16. Two barriers per 64-key tile; the Ps
// LDS buffer is strictly per-wave so no barrier is needed between its write
// and read (in-wave LDS DS ops execute in program order).
__global__ __launch_bounds__(256) void attn_mfma(__hip_bfloat16* __restrict__ proj,
                                                 const __hip_bfloat16* __restrict__ vtg) {
    __shared__ __align__(16) __hip_bfloat16 Ks[64][136];   // 64 keys x 128 d
    __shared__ __align__(16) __hip_bfloat16 Vs[128][72];   // 128 d x 64 keys
    __shared__ __align__(16) __hip_bfloat16 Ps[4][32][72]; // per-wave P tile
    // XCD-chunked swizzle (bijective: nwg=1024, %8==0): each XCD owns 8 whole
    // heads so the active head's K/V (1 MB) stays resident in its 4 MiB L2.
    const int nwg = gridDim.x * gridDim.y;
    const int f  = blockIdx.y * gridDim.x + blockIdx.x;
    const int f2 = (f & 7) * (nwg >> 3) + (f >> 3);
    const int qt = f2 & 15;            // gridDim.x == 16
    const int bh = f2 >> 4;
    const int b = bh >> 5, h = bh & 31;
    const int q0 = qt << 7;
    const int tid = threadIdx.x, wave = tid >> 6, lane = tid & 63;
    const int row16 = lane & 15, quad = lane >> 4;

    __hip_bfloat16* qb = proj + (size_t)b * SEQ * QKV + h * HD;
    const __hip_bfloat16* kb = qb + HIDDEN;
    const __hip_bfloat16* vp = vtg + (size_t)bh * HD * SEQ;

    const int wbase = q0 + wave * 32;

    bf16x8 qf[2][4];
#pragma unroll
    for (int qr = 0; qr < 2; ++qr) {
        const __hip_bfloat16* qrow = qb + (size_t)(wbase + qr * 16 + row16) * QKV + quad * 8;
#pragma unroll
        for (int s = 0; s < 4; ++s) qf[qr][s] = *(const bf16x8*)(qrow + s * 32);
    }

    f32x4 oa[2][8] = {};
    float m_i[2][4], l_i[2][4];
#pragma unroll
    for (int qr = 0; qr < 2; ++qr)
#pragma unroll
        for (int r = 0; r < 4; ++r) { m_i[qr][r] = -3.0e38f; l_i[qr][r] = 0.f; }

    const int ktmax = 2 * qt + 1;
    for (int kt = 0; kt <= ktmax; ++kt) {
        const int k0 = kt << 6;
        __syncthreads();
        for (int i = tid; i < 1024; i += 256) {
            int r = i >> 4, c = (i & 15) << 3;
            *(uint4*)&Ks[r][c] = *(const uint4*)&kb[(size_t)(k0 + r) * QKV + c];
        }
        for (int i = tid; i < 1024; i += 256) {
            int d = i >> 3, ko = (i & 7) << 3;
            *(uint4*)&Vs[d][ko] = *(const uint4*)&vp[(size_t)d * SEQ + k0 + ko];
        }
        __syncthreads();
        // Both barriers of this iteration are done; waves whose 32 rows are
        // entirely above this key tile skip the compute (wave-uniform).
        if (k0 > wbase + 31) continue;

        // S = Q K^T  (Q pre-scaled by 1/sqrt(d) in rope_kernel)
        f32x4 sf[2][4] = {};
#pragma unroll
        for (int nt = 0; nt < 4; ++nt) {
            bf16x8 kf[4];
#pragma unroll
            for (int ks = 0; ks < 4; ++ks)
                kf[ks] = *(const bf16x8*)&Ks[nt * 16 + row16][ks * 32 + quad * 8];
#pragma unroll
            for (int qr = 0; qr < 2; ++qr)
#pragma unroll
                for (int ks = 0; ks < 4; ++ks)
                    sf[qr][nt] = __builtin_amdgcn_mfma_f32_16x16x32_bf16(qf[qr][ks], kf[ks], sf[qr][nt], 0, 0, 0);
        }
        if (k0 + 63 > wbase) {          // diagonal region: causal mask
#pragma unroll
            for (int qr = 0; qr < 2; ++qr)
#pragma unroll
                for (int nt = 0; nt < 4; ++nt) {
                    int key = k0 + nt * 16 + row16;
#pragma unroll
                    for (int rg = 0; rg < 4; ++rg)
                        if (key > wbase + qr * 16 + quad * 4 + rg) sf[qr][nt][rg] = -3.0e38f;
                }
        }
        // online softmax, per 16-row fragment
#pragma unroll
        for (int qr = 0; qr < 2; ++qr) {
            float alpha[4], rs[4];
#pragma unroll
            for (int rg = 0; rg < 4; ++rg) {
                float mx = fmaxf(fmaxf(sf[qr][0][rg], sf[qr][1][rg]), fmaxf(sf[qr][2][rg], sf[qr][3][rg]));
#pragma unroll
                for (int off = 8; off > 0; off >>= 1) mx = fmaxf(mx, __shfl_xor(mx, off));
                float mn = fmaxf(m_i[qr][rg], mx);
                alpha[rg] = __expf(m_i[qr][rg] - mn);
                m_i[qr][rg] = mn;
                rs[rg] = 0.f;
            }
#pragma unroll
            for (int nt = 0; nt < 4; ++nt)
#pragma unroll
                for (int rg = 0; rg < 4; ++rg) {
                    float p = __expf(sf[qr][nt][rg] - m_i[qr][rg]);
                    rs[rg] += p;
                    Ps[wave][qr * 16 + quad * 4 + rg][nt * 16 + row16] = __float2bfloat16(p);
                }
#pragma unroll
            for (int rg = 0; rg < 4; ++rg) {
#pragma unroll
                for (int off = 8; off > 0; off >>= 1) rs[rg] += __shfl_xor(rs[rg], off);
                l_i[qr][rg] = l_i[qr][rg] * alpha[rg] + rs[rg];
            }
#pragma unroll
            for (int dt = 0; dt < 8; ++dt)
#pragma unroll
                for (int rg = 0; rg < 4; ++rg) oa[qr][dt][rg] *= alpha[rg];
        }
        __builtin_amdgcn_wave_barrier();   // compile-time order: Ps writes before reads
        bf16x8 pf[2][2];
#pragma unroll
        for (int qr = 0; qr < 2; ++qr) {
            pf[qr][0] = *(const bf16x8*)&Ps[wave][qr * 16 + row16][quad * 8];
            pf[qr][1] = *(const bf16x8*)&Ps[wave][qr * 16 + row16][32 + quad * 8];
        }
#pragma unroll
        for (int dt = 0; dt < 8; ++dt) {
            bf16x8 v0 = *(const bf16x8*)&Vs[dt * 16 + row16][quad * 8];
            bf16x8 v1 = *(const bf16x8*)&Vs[dt * 16 + row16][32 + quad * 8];
#pragma unroll
            for (int qr = 0; qr < 2; ++qr) {
                oa[qr][dt] = __builtin_amdgcn_mfma_f32_16x16x32_bf16(pf[qr][0], v0, oa[qr][dt], 0, 0, 0);
                oa[qr][dt] = __builtin_amdgcn_mfma_f32_16x16x32_bf16(pf[qr][1], v1, oa[qr][dt], 0, 0, 0);
            }
        }
    }
#pragma unroll
    for (int qr = 0; qr < 2; ++qr)
#pragma unroll
        for (int rg = 0; rg < 4; ++rg) {
            float inv = 1.0f / l_i[qr][rg];
            __hip_bfloat16* orow = qb + (size_t)(wbase + qr * 16 + quad * 4 + rg) * QKV;
#pragma unroll
            for (int dt = 0; dt < 8; ++dt)
                orow[dt * 16 + row16] = __float2bfloat16(oa[qr][dt][rg] * inv);
        }
}

extern "C" void kernel_launch(void* const* d_in, const int* in_sizes, int n_in,
                              void* d_out, int out_size, void* d_ws, size_t ws_size,
                              hipStream_t stream) {
    const float* hs = (const float*)d_in[0];
    const float* Wp = (const float*)d_in[3];
    const float* Wo = (const float*)d_in[4];
    float* out = (float*)d_out;

    const size_t SZ_PROJ = (size_t)MTOT * QKV;      // bf16 elems
    const size_t SZ_H    = (size_t)MTOT * HIDDEN;
    const size_t SZ_WP   = (size_t)QKV * HIDDEN;
    const size_t need = (SZ_PROJ + SZ_H + SZ_WP + SZ_H) * sizeof(__hip_bfloat16);  // 256 MiB

    __hip_bfloat16* proj = (__hip_bfloat16*)d_ws;

    if (ws_size >= need) {
        // [proj][hsb][Wpb][Wob]; vtg aliases the (dead-after-GEMM1) hsb region.
        __hip_bfloat16* hsb = proj + SZ_PROJ;
        __hip_bfloat16* Wpb = hsb + SZ_H;
        __hip_bfloat16* Wob = Wpb + SZ_WP;
        __hip_bfloat16* vtg = hsb;   // 33.6 MB, fits in hsb+Wpb (134 MB)

        cvt_bf16<<<dim3(SZ_H / 8 / 256), dim3(256), 0, stream>>>(hs, hsb, SZ_H / 8);
        cvt_bf16<<<dim3(SZ_WP / 8 / 256), dim3(256), 0, stream>>>(Wp, Wpb, SZ_WP / 8);
        cvt_bf16<<<dim3(SZ_H / 8 / 256), dim3(256), 0, stream>>>(Wo, Wob, SZ_H / 8);
        gemm_256<<<dim3(QKV / 256, MTOT / 256), dim3(512), 0, stream>>>(hsb, Wpb, proj, MTOT, QKV, HIDDEN, HIDDEN);
        rope_kernel<<<dim3((MTOT * 2 * NH * 64) / 256), dim3(256), 0, stream>>>(proj);
        transpose_v<<<dim3(SEQ / 64, BATCH * NH), dim3(256), 0, stream>>>(proj, vtg);
        attn_mfma<<<dim3(SEQ / 128, BATCH * NH), dim3(256), 0, stream>>>(proj, vtg);
        gemm_256<<<dim3(HIDDEN / 256, MTOT / 256), dim3(512), 0, stream>>>(proj, Wob, out, MTOT, HIDDEN, HIDDEN, QKV);
    } else {
        // proven 128-MiB fallback (round-4 path)
        __hip_bfloat16* vtg = proj + SZ_PROJ;
        gemm_bt<<<dim3(QKV / 128, MTOT / 128), dim3(256), 0, stream>>>(hs, Wp, proj, MTOT, QKV, HIDDEN, HIDDEN);
        rope_kernel<<<dim3((MTOT * 2 * NH * 64) / 256), dim3(256), 0, stream>>>(proj);
        transpose_v<<<dim3(SEQ / 64, BATCH * NH), dim3(256), 0, stream>>>(proj, vtg);
        attn_mfma<<<dim3(SEQ / 128, BATCH * NH), dim3(256), 0, stream>>>(proj, vtg);
        gemm_bt<<<dim3(HIDDEN / 128, MTOT / 128), dim3(256), 0, stream>>>(proj, Wo, out, MTOT, HIDDEN, HIDDEN, QKV);
    }
}

// Round 7
// 1198.616 us; speedup vs baseline: 1.0807x; 1.0807x over previous
//
#include <hip/hip_runtime.h>
#include <hip/hip_bf16.h>

typedef __bf16 bf16x8 __attribute__((ext_vector_type(8)));
typedef float f32x4 __attribute__((ext_vector_type(4)));

#define HIDDEN 4096
#define NH 32
#define HD 128
#define SEQ 2048
#define BATCH 2
#define MTOT 4096           // BATCH*SEQ
#define QKV 12288

// ---- async global->LDS, 16B per lane; LDS dest = wave-uniform base + lane*16 ----
__device__ __forceinline__ void async16(const void* g, void* l) {
    __builtin_amdgcn_global_load_lds(
        (const __attribute__((address_space(1))) void*)(uintptr_t)g,
        (__attribute__((address_space(3))) void*)(uint32_t)(uintptr_t)l,
        16, 0, 0);
}

// Load 8 source elements and return them as 8 packed bf16 (one uint4).
__device__ __forceinline__ uint4 ld8(const __hip_bfloat16* p) { return *(const uint4*)p; }
__device__ __forceinline__ uint4 ld8(const float* p) {
    float4 a = *(const float4*)p;
    float4 b = *(const float4*)(p + 4);
    __hip_bfloat16 t[8];
    t[0] = __float2bfloat16(a.x); t[1] = __float2bfloat16(a.y);
    t[2] = __float2bfloat16(a.z); t[3] = __float2bfloat16(a.w);
    t[4] = __float2bfloat16(b.x); t[5] = __float2bfloat16(b.y);
    t[6] = __float2bfloat16(b.z); t[7] = __float2bfloat16(b.w);
    return *(uint4*)t;
}

__device__ __forceinline__ void stc(__hip_bfloat16* C, size_t i, float v) { C[i] = __float2bfloat16(v); }
__device__ __forceinline__ void stc(float* C, size_t i, float v) { C[i] = v; }

// fp32 -> bf16 bulk convert, 8 elems/thread.
__global__ __launch_bounds__(256) void cvt_bf16(const float* __restrict__ src,
                                                __hip_bfloat16* __restrict__ dst, int n8) {
    int i = blockIdx.x * 256 + threadIdx.x;
    if (i < n8) *(uint4*)&dst[(size_t)i * 8] = ld8(&src[(size_t)i * 8]);
}

// 256x256-tile GEMM, BK=32, 4-slot LDS ring, counted vmcnt (T3+T4+T5).
// ROUND-3 staging pattern (measured 420 us; round-6 fragment-order source
// was 443 us from 4x VMEM request count; round-4/6 proved the 37.7M LDS
// read conflicts are fully hidden at 2 waves/SIMD -- zero-conflict variant
// gained nothing). C[M,N] = A[M,K] @ Bt[N,K]^T, bf16 in, fp32 MFMA acc.
template <typename TC>
__global__ __launch_bounds__(512) void gemm_256(const __hip_bfloat16* __restrict__ A,
                                                const __hip_bfloat16* __restrict__ Bt,
                                                TC* __restrict__ C,
                                                int M, int N, int K, int lda) {
    __shared__ __align__(16) __hip_bfloat16 As[4][256][32];   // 64 KiB
    __shared__ __align__(16) __hip_bfloat16 Bs[4][256][32];   // 64 KiB
    const int bn = blockIdx.x * 256, bm = blockIdx.y * 256;
    const int tid = threadIdx.x, wave = tid >> 6, lane = tid & 63;
    const int wm = wave >> 2, wn = wave & 3;      // 2 x 4 wave grid
    const int row16 = lane & 15, quad = lane >> 4;
    const int lr = lane >> 2;           // 0..15: row within a 16-row chunk
    const int lc = (lane & 3) * 8;      // 0,8,16,24: col chunk
    const __hip_bfloat16* Ab = A + (size_t)(bm + wave * 16 + lr) * lda + lc;
    const __hip_bfloat16* Bb = Bt + (size_t)(bn + wave * 16 + lr) * K + lc;
    const int NT = K >> 5;

    f32x4 acc[8][4] = {};

    auto stage = [&](int t) {
        const int s = t & 3;
        const int kt = t << 5;
        async16(Ab + kt,                     &As[s][wave * 16][0]);
        async16(Ab + (size_t)128 * lda + kt, &As[s][wave * 16 + 128][0]);
        async16(Bb + kt,                     &Bs[s][wave * 16][0]);
        async16(Bb + (size_t)128 * K + kt,   &Bs[s][wave * 16 + 128][0]);
    };

    stage(0); stage(1); stage(2);       // 12 loads in flight

    for (int t = 0; t < NT; ++t) {
        const int s = t & 3;
        const int rem = NT - 1 - t;
        if (rem >= 2)      asm volatile("s_waitcnt vmcnt(8)" ::: "memory");
        else if (rem == 1) asm volatile("s_waitcnt vmcnt(4)" ::: "memory");
        else               asm volatile("s_waitcnt vmcnt(0)" ::: "memory");
        __builtin_amdgcn_s_barrier();
        __builtin_amdgcn_sched_barrier(0);
        if (t + 3 < NT) stage(t + 3);
        bf16x8 af[8], bf[4];
#pragma unroll
        for (int i = 0; i < 8; ++i)
            af[i] = *(const bf16x8*)&As[s][wm * 128 + i * 16 + row16][quad * 8];
#pragma unroll
        for (int j = 0; j < 4; ++j)
            bf[j] = *(const bf16x8*)&Bs[s][wn * 64 + j * 16 + row16][quad * 8];
        __builtin_amdgcn_s_setprio(1);
#pragma unroll
        for (int i = 0; i < 8; ++i)
#pragma unroll
            for (int j = 0; j < 4; ++j)
                acc[i][j] = __builtin_amdgcn_mfma_f32_16x16x32_bf16(af[i], bf[j], acc[i][j], 0, 0, 0);
        __builtin_amdgcn_s_setprio(0);
    }

    const int col0 = bn + wn * 64 + row16;
    const int row0 = bm + wm * 128 + quad * 4;
#pragma unroll
    for (int i = 0; i < 8; ++i)
#pragma unroll
        for (int j = 0; j < 4; ++j)
#pragma unroll
            for (int rg = 0; rg < 4; ++rg)
                stc(C, (size_t)(row0 + i * 16 + rg) * N + col0 + j * 16, acc[i][j][rg]);
}

// Fallback GEMM (fp32 or bf16 inputs via ld8 staging). Used when ws is small.
template <typename TA, typename TB, typename TC>
__global__ __launch_bounds__(256) void gemm_bt(const TA* __restrict__ A,
                                               const TB* __restrict__ Bt,
                                               TC* __restrict__ C,
                                               int M, int N, int K, int lda) {
    __shared__ __align__(16) __hip_bfloat16 As[128][32];
    __shared__ __align__(16) __hip_bfloat16 Bs[128][32];
    const int bn = blockIdx.x * 128, bm = blockIdx.y * 128;
    const int tid = threadIdx.x, wave = tid >> 6, lane = tid & 63;
    const int wm = (wave >> 1) * 64, wn = (wave & 1) * 64;
    const int row16 = lane & 15, quad = lane >> 4;
    const int arow = tid >> 2;
    const int acol = (tid & 3) * 8;

    f32x4 acc[4][4] = {};

    for (int kt = 0; kt < K; kt += 32) {
        __syncthreads();
#pragma unroll
        for (int it = 0; it < 2; ++it) {
            int r = arow + it * 64;
            *(uint4*)&As[r][acol] = ld8(&A[(size_t)(bm + r) * lda + kt + acol]);
            *(uint4*)&Bs[r][acol] = ld8(&Bt[(size_t)(bn + r) * K + kt + acol]);
        }
        __syncthreads();
        bf16x8 af[4], bf[4];
#pragma unroll
        for (int i = 0; i < 4; ++i) af[i] = *(const bf16x8*)&As[wm + i * 16 + row16][quad * 8];
#pragma unroll
        for (int j = 0; j < 4; ++j) bf[j] = *(const bf16x8*)&Bs[wn + j * 16 + row16][quad * 8];
#pragma unroll
        for (int i = 0; i < 4; ++i)
#pragma unroll
            for (int j = 0; j < 4; ++j)
                acc[i][j] = __builtin_amdgcn_mfma_f32_16x16x32_bf16(af[i], bf[j], acc[i][j], 0, 0, 0);
    }
    const int col0 = bn + wn + row16;
    const int row0 = bm + wm + quad * 4;
#pragma unroll
    for (int i = 0; i < 4; ++i)
#pragma unroll
        for (int j = 0; j < 4; ++j)
#pragma unroll
            for (int rg = 0; rg < 4; ++rg)
                stc(C, (size_t)(row0 + i * 16 + rg) * N + col0 + j * 16, acc[i][j][rg]);
}

// In-place RoPE on the Q and K thirds of proj[MTOT][QKV]. position = row % SEQ.
// Q rows additionally pre-scaled by 1/sqrt(HD) so attn skips the score scaling.
__global__ __launch_bounds__(256) void rope_kernel(__hip_bfloat16* __restrict__ proj) {
    int t = blockIdx.x * 256 + threadIdx.x;
    int j = t & 63;
    int head = (t >> 6) & 31;
    int mat = (t >> 11) & 1;
    int row = t >> 12;
    int pos = row & (SEQ - 1);
    float invf = __expf(-(float)j * 0.14391156514261f);   // 10000^(-j/64)
    float ang = (float)pos * invf;
    float rev = ang * 0.15915494309189535f;               // range-reduce for v_sin/v_cos
    rev -= floorf(rev);
    float arad = rev * 6.283185307179586f;
    float sn = __sinf(arad);
    float cs = __cosf(arad);
    if (mat == 0) {                     // Q third: fold in 1/sqrt(128)
        sn *= 0.08838834764831845f;
        cs *= 0.08838834764831845f;
    }
    size_t base = (size_t)row * QKV + mat * HIDDEN + head * HD + j;
    float x1 = __bfloat162float(proj[base]);
    float x2 = __bfloat162float(proj[base + 64]);
    proj[base]      = __float2bfloat16(x1 * cs - x2 * sn);
    proj[base + 64] = __float2bfloat16(x2 * cs + x1 * sn);
}

// One-shot V transpose: proj V-third [b][s][h*128+d] -> vtg[(b*32+h)][d][s].
__global__ __launch_bounds__(256) void transpose_v(const __hip_bfloat16* __restrict__ proj,
                                                   __hip_bfloat16* __restrict__ vtg) {
    __shared__ __hip_bfloat16 Ls[64][132];
    const int st = blockIdx.x, bh = blockIdx.y;
    const int b = bh >> 5, h = bh & 31;
    const int s0 = st << 6;
    const int tid = threadIdx.x;
    const __hip_bfloat16* vb = proj + (size_t)b * SEQ * QKV + 2 * HIDDEN + h * HD;
    for (int i = tid; i < 1024; i += 256) {
        int r = i >> 4, c = (i & 15) << 3;
        uint4 raw = *(const uint4*)&vb[(size_t)(s0 + r) * QKV + c];
        *(uint2*)&Ls[r][c]     = make_uint2(raw.x, raw.y);
        *(uint2*)&Ls[r][c + 4] = make_uint2(raw.z, raw.w);
    }
    __syncthreads();
    __hip_bfloat16* ob = vtg + (size_t)bh * HD * SEQ + s0;
    for (int t = tid; t < 1024; t += 256) {
        int d = t >> 3, sc = (t & 7) << 3;
        __hip_bfloat16 tmp[8];
#pragma unroll
        for (int x = 0; x < 8; ++x) tmp[x] = Ls[sc + x][d];
        *(uint4*)&ob[(size_t)d * SEQ + sc] = *(uint4*)tmp;
    }
}

// MFMA flash attention, ring-staged. Block = 256 q-rows x (b,h); 8 waves x
// 32 q-rows. K/V staged via global_load_lds into fragment-ordered 1-KiB
// blocks (lane L of block (nt,ks) holds K[nt*16+(L&15)][ks*32+(L>>4)*8]),
// 2-slot ring, ONE barrier per 64-key tile: stage(t+1) issues before
// compute(t); vmcnt(0) drains after the full QK+softmax+PV phase (covered).
// Overwrite audit: stage(t+1) targets slot (t+1)&1, last read in iteration
// t-1 whose end-of-iteration barrier precedes this issue. LDS reads are at
// block_base + lane*16 -- conflict-free by construction. Requires
// gridDim.x == SEQ/256 == 8.
__global__ __launch_bounds__(512) void attn_mfma(__hip_bfloat16* __restrict__ proj,
                                                 const __hip_bfloat16* __restrict__ vtg) {
    __shared__ __align__(16) __hip_bfloat16 Kf[2][16][512];  // 32 KiB, blocks (nt*4+ks)
    __shared__ __align__(16) __hip_bfloat16 Vf[2][16][512];  // 32 KiB, blocks (dt*2+kh)
    __shared__ __align__(16) __hip_bfloat16 Ps[8][32][72];   // 36 KiB, per-wave P tile
    // XCD-chunked swizzle (bijective: nwg=512, %8==0): chunks of 64 blocks
    // per XCD = 8 heads x all 8 q-tiles -> K/V L2-resident + load-balanced.
    const int nwg = gridDim.x * gridDim.y;
    const int f  = blockIdx.y * gridDim.x + blockIdx.x;
    const int f2 = (f & 7) * (nwg >> 3) + (f >> 3);
    const int qt = f2 & 7;             // gridDim.x == 8
    const int bh = f2 >> 3;
    const int b = bh >> 5, h = bh & 31;
    const int q0 = qt << 8;
    const int tid = threadIdx.x, wave = tid >> 6, lane = tid & 63;
    const int row16 = lane & 15, quad = lane >> 4;

    __hip_bfloat16* qb = proj + (size_t)b * SEQ * QKV + h * HD;
    const __hip_bfloat16* kb = qb + HIDDEN;
    const __hip_bfloat16* vp = vtg + (size_t)bh * HD * SEQ;

    const int wbase = q0 + wave * 32;

    // this wave's two staging blocks (uniform per wave)
    const int b0 = 2 * wave, b1 = 2 * wave + 1;
    const __hip_bfloat16* ks0 = kb + (size_t)((b0 >> 2) * 16 + row16) * QKV + (b0 & 3) * 32 + quad * 8;
    const __hip_bfloat16* ks1 = kb + (size_t)((b1 >> 2) * 16 + row16) * QKV + (b1 & 3) * 32 + quad * 8;
    const __hip_bfloat16* vs0 = vp + (size_t)((b0 >> 1) * 16 + row16) * SEQ + (b0 & 1) * 32 + quad * 8;
    const __hip_bfloat16* vs1 = vp + (size_t)((b1 >> 1) * 16 + row16) * SEQ + (b1 & 1) * 32 + quad * 8;

    auto stage = [&](int kt) {
        const int s = kt & 1;
        const int k0 = kt << 6;
        async16(ks0 + (size_t)k0 * QKV, &Kf[s][b0][0]);
        async16(ks1 + (size_t)k0 * QKV, &Kf[s][b1][0]);
        async16(vs0 + k0,               &Vf[s][b0][0]);
        async16(vs1 + k0,               &Vf[s][b1][0]);
    };

    bf16x8 qf[2][4];
#pragma unroll
    for (int qr = 0; qr < 2; ++qr) {
        const __hip_bfloat16* qrow = qb + (size_t)(wbase + qr * 16 + row16) * QKV + quad * 8;
#pragma unroll
        for (int s = 0; s < 4; ++s) qf[qr][s] = *(const bf16x8*)(qrow + s * 32);
    }

    f32x4 oa[2][8] = {};
    float m_i[2][4], l_i[2][4];
#pragma unroll
    for (int qr = 0; qr < 2; ++qr)
#pragma unroll
        for (int r = 0; r < 4; ++r) { m_i[qr][r] = -3.0e38f; l_i[qr][r] = 0.f; }

    stage(0);
    asm volatile("s_waitcnt vmcnt(0)" ::: "memory");
    __builtin_amdgcn_s_barrier();
    __builtin_amdgcn_sched_barrier(0);

    const int ktmax = 4 * qt + 3;
    for (int kt = 0; kt <= ktmax; ++kt) {
        const int s = kt & 1;
        const int k0 = kt << 6;
        if (kt < ktmax) stage(kt + 1);
        if (k0 <= wbase + 31) {          // wave-uniform active test
            // S = Q K^T  (Q pre-scaled by 1/sqrt(d) in rope_kernel)
            f32x4 sf[2][4] = {};
#pragma unroll
            for (int nt = 0; nt < 4; ++nt) {
                bf16x8 kf[4];
#pragma unroll
                for (int ks = 0; ks < 4; ++ks)
                    kf[ks] = *(const bf16x8*)&Kf[s][nt * 4 + ks][lane * 8];
#pragma unroll
                for (int qr = 0; qr < 2; ++qr)
#pragma unroll
                    for (int ks = 0; ks < 4; ++ks)
                        sf[qr][nt] = __builtin_amdgcn_mfma_f32_16x16x32_bf16(qf[qr][ks], kf[ks], sf[qr][nt], 0, 0, 0);
            }
            if (k0 + 63 > wbase) {       // diagonal region: causal mask
#pragma unroll
                for (int qr = 0; qr < 2; ++qr)
#pragma unroll
                    for (int nt = 0; nt < 4; ++nt) {
                        int key = k0 + nt * 16 + row16;
#pragma unroll
                        for (int rg = 0; rg < 4; ++rg)
                            if (key > wbase + qr * 16 + quad * 4 + rg) sf[qr][nt][rg] = -3.0e38f;
                    }
            }
            // online softmax, per 16-row fragment
#pragma unroll
            for (int qr = 0; qr < 2; ++qr) {
                float alpha[4], rs[4];
#pragma unroll
                for (int rg = 0; rg < 4; ++rg) {
                    float mx = fmaxf(fmaxf(sf[qr][0][rg], sf[qr][1][rg]), fmaxf(sf[qr][2][rg], sf[qr][3][rg]));
#pragma unroll
                    for (int off = 8; off > 0; off >>= 1) mx = fmaxf(mx, __shfl_xor(mx, off));
                    float mn = fmaxf(m_i[qr][rg], mx);
                    alpha[rg] = __expf(m_i[qr][rg] - mn);
                    m_i[qr][rg] = mn;
                    rs[rg] = 0.f;
                }
#pragma unroll
                for (int nt = 0; nt < 4; ++nt)
#pragma unroll
                    for (int rg = 0; rg < 4; ++rg) {
                        float p = __expf(sf[qr][nt][rg] - m_i[qr][rg]);
                        rs[rg] += p;
                        Ps[wave][qr * 16 + quad * 4 + rg][nt * 16 + row16] = __float2bfloat16(p);
                    }
#pragma unroll
                for (int rg = 0; rg < 4; ++rg) {
#pragma unroll
                    for (int off = 8; off > 0; off >>= 1) rs[rg] += __shfl_xor(rs[rg], off);
                    l_i[qr][rg] = l_i[qr][rg] * alpha[rg] + rs[rg];
                }
#pragma unroll
                for (int dt = 0; dt < 8; ++dt)
#pragma unroll
                    for (int rg = 0; rg < 4; ++rg) oa[qr][dt][rg] *= alpha[rg];
            }
            __builtin_amdgcn_wave_barrier();   // order Ps writes before reads (same wave)
            bf16x8 pf[2][2];
#pragma unroll
            for (int qr = 0; qr < 2; ++qr) {
                pf[qr][0] = *(const bf16x8*)&Ps[wave][qr * 16 + row16][quad * 8];
                pf[qr][1] = *(const bf16x8*)&Ps[wave][qr * 16 + row16][32 + quad * 8];
            }
#pragma unroll
            for (int dt = 0; dt < 8; ++dt) {
                bf16x8 v0 = *(const bf16x8*)&Vf[s][dt * 2][lane * 8];
                bf16x8 v1 = *(const bf16x8*)&Vf[s][dt * 2 + 1][lane * 8];
#pragma unroll
                for (int qr = 0; qr < 2; ++qr) {
                    oa[qr][dt] = __builtin_amdgcn_mfma_f32_16x16x32_bf16(pf[qr][0], v0, oa[qr][dt], 0, 0, 0);
                    oa[qr][dt] = __builtin_amdgcn_mfma_f32_16x16x32_bf16(pf[qr][1], v1, oa[qr][dt], 0, 0, 0);
                }
            }
        }
        // stage(kt+1) landed (own 4 loads) + all waves done reading slot s
        asm volatile("s_waitcnt vmcnt(0)" ::: "memory");
        __builtin_amdgcn_s_barrier();
        __builtin_amdgcn_sched_barrier(0);
    }
#pragma unroll
    for (int qr = 0; qr < 2; ++qr)
#pragma unroll
        for (int rg = 0; rg < 4; ++rg) {
            float inv = 1.0f / l_i[qr][rg];
            __hip_bfloat16* orow = qb + (size_t)(wbase + qr * 16 + quad * 4 + rg) * QKV;
#pragma unroll
            for (int dt = 0; dt < 8; ++dt)
                orow[dt * 16 + row16] = __float2bfloat16(oa[qr][dt][rg] * inv);
        }
}

extern "C" void kernel_launch(void* const* d_in, const int* in_sizes, int n_in,
                              void* d_out, int out_size, void* d_ws, size_t ws_size,
                              hipStream_t stream) {
    const float* hs = (const float*)d_in[0];
    const float* Wp = (const float*)d_in[3];
    const float* Wo = (const float*)d_in[4];
    float* out = (float*)d_out;

    const size_t SZ_PROJ = (size_t)MTOT * QKV;      // bf16 elems
    const size_t SZ_H    = (size_t)MTOT * HIDDEN;
    const size_t SZ_WP   = (size_t)QKV * HIDDEN;
    const size_t need = (SZ_PROJ + SZ_H + SZ_WP + SZ_H) * sizeof(__hip_bfloat16);  // 256 MiB

    __hip_bfloat16* proj = (__hip_bfloat16*)d_ws;

    if (ws_size >= need) {
        // [proj][hsb][Wpb][Wob]; vtg aliases the (dead-after-GEMM1) hsb region.
        __hip_bfloat16* hsb = proj + SZ_PROJ;
        __hip_bfloat16* Wpb = hsb + SZ_H;
        __hip_bfloat16* Wob = Wpb + SZ_WP;
        __hip_bfloat16* vtg = hsb;   // 33.6 MB, fits in hsb+Wpb (134 MB)

        cvt_bf16<<<dim3(SZ_H / 8 / 256), dim3(256), 0, stream>>>(hs, hsb, SZ_H / 8);
        cvt_bf16<<<dim3(SZ_WP / 8 / 256), dim3(256), 0, stream>>>(Wp, Wpb, SZ_WP / 8);
        cvt_bf16<<<dim3(SZ_H / 8 / 256), dim3(256), 0, stream>>>(Wo, Wob, SZ_H / 8);
        gemm_256<<<dim3(QKV / 256, MTOT / 256), dim3(512), 0, stream>>>(hsb, Wpb, proj, MTOT, QKV, HIDDEN, HIDDEN);
        rope_kernel<<<dim3((MTOT * 2 * NH * 64) / 256), dim3(256), 0, stream>>>(proj);
        transpose_v<<<dim3(SEQ / 64, BATCH * NH), dim3(256), 0, stream>>>(proj, vtg);
        attn_mfma<<<dim3(SEQ / 256, BATCH * NH), dim3(512), 0, stream>>>(proj, vtg);
        gemm_256<<<dim3(HIDDEN / 256, MTOT / 256), dim3(512), 0, stream>>>(proj, Wob, out, MTOT, HIDDEN, HIDDEN, QKV);
    } else {
        // proven 128-MiB fallback (round-4 path)
        __hip_bfloat16* vtg = proj + SZ_PROJ;
        gemm_bt<<<dim3(QKV / 128, MTOT / 128), dim3(256), 0, stream>>>(hs, Wp, proj, MTOT, QKV, HIDDEN, HIDDEN);
        rope_kernel<<<dim3((MTOT * 2 * NH * 64) / 256), dim3(256), 0, stream>>>(proj);
        transpose_v<<<dim3(SEQ / 64, BATCH * NH), dim3(256), 0, stream>>>(proj, vtg);
        attn_mfma<<<dim3(SEQ / 256, BATCH * NH), dim3(512), 0, stream>>>(proj, vtg);
        gemm_bt<<<dim3(HIDDEN / 128, MTOT / 128), dim3(256), 0, stream>>>(proj, Wo, out, MTOT, HIDDEN, HIDDEN, QKV);
    }
}

// Round 8
// 1110.318 us; speedup vs baseline: 1.1666x; 1.0795x over previous
//
#include <hip/hip_runtime.h>
#include <hip/hip_bf16.h>

typedef __bf16 bf16x8 __attribute__((ext_vector_type(8)));
typedef float f32x4 __attribute__((ext_vector_type(4)));

#define HIDDEN 4096
#define NH 32
#define HD 128
#define SEQ 2048
#define BATCH 2
#define MTOT 4096           // BATCH*SEQ
#define QKV 12288

// ---- async global->LDS, 16B per lane; LDS dest = wave-uniform base + lane*16 ----
__device__ __forceinline__ void async16(const void* g, void* l) {
    __builtin_amdgcn_global_load_lds(
        (const __attribute__((address_space(1))) void*)(uintptr_t)g,
        (__attribute__((address_space(3))) void*)(uint32_t)(uintptr_t)l,
        16, 0, 0);
}

// Load 8 source elements and return them as 8 packed bf16 (one uint4).
__device__ __forceinline__ uint4 ld8(const __hip_bfloat16* p) { return *(const uint4*)p; }
__device__ __forceinline__ uint4 ld8(const float* p) {
    float4 a = *(const float4*)p;
    float4 b = *(const float4*)(p + 4);
    __hip_bfloat16 t[8];
    t[0] = __float2bfloat16(a.x); t[1] = __float2bfloat16(a.y);
    t[2] = __float2bfloat16(a.z); t[3] = __float2bfloat16(a.w);
    t[4] = __float2bfloat16(b.x); t[5] = __float2bfloat16(b.y);
    t[6] = __float2bfloat16(b.z); t[7] = __float2bfloat16(b.w);
    return *(uint4*)t;
}

__device__ __forceinline__ void stc(__hip_bfloat16* C, size_t i, float v) { C[i] = __float2bfloat16(v); }
__device__ __forceinline__ void stc(float* C, size_t i, float v) { C[i] = v; }

// fp32 -> bf16 bulk convert, 8 elems/thread.
__global__ __launch_bounds__(256) void cvt_bf16(const float* __restrict__ src,
                                                __hip_bfloat16* __restrict__ dst, int n8) {
    int i = blockIdx.x * 256 + threadIdx.x;
    if (i < n8) *(uint4*)&dst[(size_t)i * 8] = ld8(&src[(size_t)i * 8]);
}

// 256x256-tile GEMM, BK=64, 2-slot LDS ring, ONE barrier per K-step.
// C[M,N] = A[M,K] @ Bt[N,K]^T, bf16 in, fp32 MFMA acc. 8 waves (2M x 4N),
// per-wave output 128x64 (acc[8][4]), 64 MFMA per wave per barrier (2x the
// round-3 BK=32 kernel -- halves the ~970cy/step fixed barrier stall).
//
// Pipeline: stage(t+1) issues right after the barrier; the vmcnt(0) at the
// NEXT iteration's top waits on loads issued a full iteration (~4.3k cy)
// earlier, so the wait is ~free (issue-early is what matters, not the
// count). Slot safety: stage(t+1) targets slot s^1, last read in iter t-1;
// all waves passed this iter's barrier => those reads are done.
//
// Swizzle (both-sides, rule #21): at 128B row stride a naive b128 read is
// 16-way (2x above the 8-lane/column b128 floor). Store logical 16B chunk c
// of row r at physical chunk c^(r&7); the global SOURCE chunk is
// pre-permuted per-lane ((lane&7)^(lane>>3) -- involution within each row,
// coalescing unchanged: 8 lanes still cover one contiguous 128B row), LDS
// write stays linear, and reads apply the same XOR -> floor restored.
template <typename TC>
__global__ __launch_bounds__(512) void gemm_256(const __hip_bfloat16* __restrict__ A,
                                                const __hip_bfloat16* __restrict__ Bt,
                                                TC* __restrict__ C,
                                                int M, int N, int K, int lda) {
    __shared__ __align__(16) __hip_bfloat16 As[2][256][64];   // 64 KiB
    __shared__ __align__(16) __hip_bfloat16 Bs[2][256][64];   // 64 KiB
    const int bn = blockIdx.x * 256, bm = blockIdx.y * 256;
    const int tid = threadIdx.x, wave = tid >> 6, lane = tid & 63;
    const int wm = wave >> 2, wn = wave & 3;      // 2 x 4 wave grid
    const int row16 = lane & 15, quad = lane >> 4;
    const int srow = lane >> 3;                   // 0..7: row within 8-row strip
    const int schunk = (lane & 7) ^ srow;         // pre-swizzled source chunk
    const __hip_bfloat16* Ab = A + (size_t)(bm + wave * 8 + srow) * lda + schunk * 8;
    const __hip_bfloat16* Bb = Bt + (size_t)(bn + wave * 8 + srow) * K + schunk * 8;
    const int NT = K >> 6;

    f32x4 acc[8][4] = {};

    auto stage = [&](int t) {
        const int s = t & 1;
        const size_t kt = (size_t)t << 6;
#pragma unroll
        for (int k = 0; k < 4; ++k) {
            async16(Ab + (size_t)(k * 64) * lda + kt, &As[s][k * 64 + wave * 8][0]);
            async16(Bb + (size_t)(k * 64) * K  + kt, &Bs[s][k * 64 + wave * 8][0]);
        }
    };

    stage(0);

    for (int t = 0; t < NT; ++t) {
        const int s = t & 1;
        asm volatile("s_waitcnt vmcnt(0)" ::: "memory");   // loads issued 1 iter ago
        __builtin_amdgcn_s_barrier();
        if (t + 1 < NT) stage(t + 1);
        __builtin_amdgcn_sched_barrier(0);                 // pin stage before compute
        const int pcb = (quad ^ (row16 & 7)) * 8;          // ks=0 physical chunk
        const int pcb1 = ((4 + quad) ^ (row16 & 7)) * 8;   // ks=1 physical chunk
#pragma unroll
        for (int ks = 0; ks < 2; ++ks) {
            const int pc = ks ? pcb1 : pcb;
            bf16x8 af[8], bf[4];
#pragma unroll
            for (int i = 0; i < 8; ++i)
                af[i] = *(const bf16x8*)&As[s][wm * 128 + i * 16 + row16][pc];
#pragma unroll
            for (int j = 0; j < 4; ++j)
                bf[j] = *(const bf16x8*)&Bs[s][wn * 64 + j * 16 + row16][pc];
            __builtin_amdgcn_s_setprio(1);
#pragma unroll
            for (int i = 0; i < 8; ++i)
#pragma unroll
                for (int j = 0; j < 4; ++j)
                    acc[i][j] = __builtin_amdgcn_mfma_f32_16x16x32_bf16(af[i], bf[j], acc[i][j], 0, 0, 0);
            __builtin_amdgcn_s_setprio(0);
        }
    }

    const int col0 = bn + wn * 64 + row16;
    const int row0 = bm + wm * 128 + quad * 4;
#pragma unroll
    for (int i = 0; i < 8; ++i)
#pragma unroll
        for (int j = 0; j < 4; ++j)
#pragma unroll
            for (int rg = 0; rg < 4; ++rg)
                stc(C, (size_t)(row0 + i * 16 + rg) * N + col0 + j * 16, acc[i][j][rg]);
}

// Fallback GEMM (fp32 or bf16 inputs via ld8 staging). Used when ws is small.
template <typename TA, typename TB, typename TC>
__global__ __launch_bounds__(256) void gemm_bt(const TA* __restrict__ A,
                                               const TB* __restrict__ Bt,
                                               TC* __restrict__ C,
                                               int M, int N, int K, int lda) {
    __shared__ __align__(16) __hip_bfloat16 As[128][32];
    __shared__ __align__(16) __hip_bfloat16 Bs[128][32];
    const int bn = blockIdx.x * 128, bm = blockIdx.y * 128;
    const int tid = threadIdx.x, wave = tid >> 6, lane = tid & 63;
    const int wm = (wave >> 1) * 64, wn = (wave & 1) * 64;
    const int row16 = lane & 15, quad = lane >> 4;
    const int arow = tid >> 2;
    const int acol = (tid & 3) * 8;

    f32x4 acc[4][4] = {};

    for (int kt = 0; kt < K; kt += 32) {
        __syncthreads();
#pragma unroll
        for (int it = 0; it < 2; ++it) {
            int r = arow + it * 64;
            *(uint4*)&As[r][acol] = ld8(&A[(size_t)(bm + r) * lda + kt + acol]);
            *(uint4*)&Bs[r][acol] = ld8(&Bt[(size_t)(bn + r) * K + kt + acol]);
        }
        __syncthreads();
        bf16x8 af[4], bf[4];
#pragma unroll
        for (int i = 0; i < 4; ++i) af[i] = *(const bf16x8*)&As[wm + i * 16 + row16][quad * 8];
#pragma unroll
        for (int j = 0; j < 4; ++j) bf[j] = *(const bf16x8*)&Bs[wn + j * 16 + row16][quad * 8];
#pragma unroll
        for (int i = 0; i < 4; ++i)
#pragma unroll
            for (int j = 0; j < 4; ++j)
                acc[i][j] = __builtin_amdgcn_mfma_f32_16x16x32_bf16(af[i], bf[j], acc[i][j], 0, 0, 0);
    }
    const int col0 = bn + wn + row16;
    const int row0 = bm + wm + quad * 4;
#pragma unroll
    for (int i = 0; i < 4; ++i)
#pragma unroll
        for (int j = 0; j < 4; ++j)
#pragma unroll
            for (int rg = 0; rg < 4; ++rg)
                stc(C, (size_t)(row0 + i * 16 + rg) * N + col0 + j * 16, acc[i][j][rg]);
}

// In-place RoPE on the Q and K thirds of proj[MTOT][QKV]. position = row % SEQ.
// Q rows additionally pre-scaled by 1/sqrt(HD) so attn skips the score scaling.
__global__ __launch_bounds__(256) void rope_kernel(__hip_bfloat16* __restrict__ proj) {
    int t = blockIdx.x * 256 + threadIdx.x;
    int j = t & 63;
    int head = (t >> 6) & 31;
    int mat = (t >> 11) & 1;
    int row = t >> 12;
    int pos = row & (SEQ - 1);
    float invf = __expf(-(float)j * 0.14391156514261f);   // 10000^(-j/64)
    float ang = (float)pos * invf;
    float rev = ang * 0.15915494309189535f;               // range-reduce for v_sin/v_cos
    rev -= floorf(rev);
    float arad = rev * 6.283185307179586f;
    float sn = __sinf(arad);
    float cs = __cosf(arad);
    if (mat == 0) {                     // Q third: fold in 1/sqrt(128)
        sn *= 0.08838834764831845f;
        cs *= 0.08838834764831845f;
    }
    size_t base = (size_t)row * QKV + mat * HIDDEN + head * HD + j;
    float x1 = __bfloat162float(proj[base]);
    float x2 = __bfloat162float(proj[base + 64]);
    proj[base]      = __float2bfloat16(x1 * cs - x2 * sn);
    proj[base + 64] = __float2bfloat16(x2 * cs + x1 * sn);
}

// One-shot V transpose: proj V-third [b][s][h*128+d] -> vtg[(b*32+h)][d][s].
__global__ __launch_bounds__(256) void transpose_v(const __hip_bfloat16* __restrict__ proj,
                                                   __hip_bfloat16* __restrict__ vtg) {
    __shared__ __hip_bfloat16 Ls[64][132];
    const int st = blockIdx.x, bh = blockIdx.y;
    const int b = bh >> 5, h = bh & 31;
    const int s0 = st << 6;
    const int tid = threadIdx.x;
    const __hip_bfloat16* vb = proj + (size_t)b * SEQ * QKV + 2 * HIDDEN + h * HD;
    for (int i = tid; i < 1024; i += 256) {
        int r = i >> 4, c = (i & 15) << 3;
        uint4 raw = *(const uint4*)&vb[(size_t)(s0 + r) * QKV + c];
        *(uint2*)&Ls[r][c]     = make_uint2(raw.x, raw.y);
        *(uint2*)&Ls[r][c + 4] = make_uint2(raw.z, raw.w);
    }
    __syncthreads();
    __hip_bfloat16* ob = vtg + (size_t)bh * HD * SEQ + s0;
    for (int t = tid; t < 1024; t += 256) {
        int d = t >> 3, sc = (t & 7) << 3;
        __hip_bfloat16 tmp[8];
#pragma unroll
        for (int x = 0; x < 8; ++x) tmp[x] = Ls[sc + x][d];
        *(uint4*)&ob[(size_t)d * SEQ + sc] = *(uint4*)tmp;
    }
}

// MFMA flash attention, ring-staged. Block = 256 q-rows x (b,h); 8 waves x
// 32 q-rows. K/V staged via global_load_lds into fragment-ordered 1-KiB
// blocks, 2-slot ring, ONE barrier per 64-key tile (round-7 verified).
__global__ __launch_bounds__(512) void attn_mfma(__hip_bfloat16* __restrict__ proj,
                                                 const __hip_bfloat16* __restrict__ vtg) {
    __shared__ __align__(16) __hip_bfloat16 Kf[2][16][512];  // 32 KiB
    __shared__ __align__(16) __hip_bfloat16 Vf[2][16][512];  // 32 KiB
    __shared__ __align__(16) __hip_bfloat16 Ps[8][32][72];   // 36 KiB
    const int nwg = gridDim.x * gridDim.y;
    const int f  = blockIdx.y * gridDim.x + blockIdx.x;
    const int f2 = (f & 7) * (nwg >> 3) + (f >> 3);
    const int qt = f2 & 7;             // gridDim.x == 8
    const int bh = f2 >> 3;
    const int b = bh >> 5, h = bh & 31;
    const int q0 = qt << 8;
    const int tid = threadIdx.x, wave = tid >> 6, lane = tid & 63;
    const int row16 = lane & 15, quad = lane >> 4;

    __hip_bfloat16* qb = proj + (size_t)b * SEQ * QKV + h * HD;
    const __hip_bfloat16* kb = qb + HIDDEN;
    const __hip_bfloat16* vp = vtg + (size_t)bh * HD * SEQ;

    const int wbase = q0 + wave * 32;

    const int b0 = 2 * wave, b1 = 2 * wave + 1;
    const __hip_bfloat16* ks0 = kb + (size_t)((b0 >> 2) * 16 + row16) * QKV + (b0 & 3) * 32 + quad * 8;
    const __hip_bfloat16* ks1 = kb + (size_t)((b1 >> 2) * 16 + row16) * QKV + (b1 & 3) * 32 + quad * 8;
    const __hip_bfloat16* vs0 = vp + (size_t)((b0 >> 1) * 16 + row16) * SEQ + (b0 & 1) * 32 + quad * 8;
    const __hip_bfloat16* vs1 = vp + (size_t)((b1 >> 1) * 16 + row16) * SEQ + (b1 & 1) * 32 + quad * 8;

    auto stage = [&](int kt) {
        const int s = kt & 1;
        const int k0 = kt << 6;
        async16(ks0 + (size_t)k0 * QKV, &Kf[s][b0][0]);
        async16(ks1 + (size_t)k0 * QKV, &Kf[s][b1][0]);
        async16(vs0 + k0,               &Vf[s][b0][0]);
        async16(vs1 + k0,               &Vf[s][b1][0]);
    };

    bf16x8 qf[2][4];
#pragma unroll
    for (int qr = 0; qr < 2; ++qr) {
        const __hip_bfloat16* qrow = qb + (size_t)(wbase + qr * 16 + row16) * QKV + quad * 8;
#pragma unroll
        for (int s = 0; s < 4; ++s) qf[qr][s] = *(const bf16x8*)(qrow + s * 32);
    }

    f32x4 oa[2][8] = {};
    float m_i[2][4], l_i[2][4];
#pragma unroll
    for (int qr = 0; qr < 2; ++qr)
#pragma unroll
        for (int r = 0; r < 4; ++r) { m_i[qr][r] = -3.0e38f; l_i[qr][r] = 0.f; }

    stage(0);
    asm volatile("s_waitcnt vmcnt(0)" ::: "memory");
    __builtin_amdgcn_s_barrier();
    __builtin_amdgcn_sched_barrier(0);

    const int ktmax = 4 * qt + 3;
    for (int kt = 0; kt <= ktmax; ++kt) {
        const int s = kt & 1;
        const int k0 = kt << 6;
        if (kt < ktmax) stage(kt + 1);
        if (k0 <= wbase + 31) {          // wave-uniform active test
            f32x4 sf[2][4] = {};
#pragma unroll
            for (int nt = 0; nt < 4; ++nt) {
                bf16x8 kf[4];
#pragma unroll
                for (int ks = 0; ks < 4; ++ks)
                    kf[ks] = *(const bf16x8*)&Kf[s][nt * 4 + ks][lane * 8];
#pragma unroll
                for (int qr = 0; qr < 2; ++qr)
#pragma unroll
                    for (int ks = 0; ks < 4; ++ks)
                        sf[qr][nt] = __builtin_amdgcn_mfma_f32_16x16x32_bf16(qf[qr][ks], kf[ks], sf[qr][nt], 0, 0, 0);
            }
            if (k0 + 63 > wbase) {       // diagonal region: causal mask
#pragma unroll
                for (int qr = 0; qr < 2; ++qr)
#pragma unroll
                    for (int nt = 0; nt < 4; ++nt) {
                        int key = k0 + nt * 16 + row16;
#pragma unroll
                        for (int rg = 0; rg < 4; ++rg)
                            if (key > wbase + qr * 16 + quad * 4 + rg) sf[qr][nt][rg] = -3.0e38f;
                    }
            }
#pragma unroll
            for (int qr = 0; qr < 2; ++qr) {
                float alpha[4], rs[4];
#pragma unroll
                for (int rg = 0; rg < 4; ++rg) {
                    float mx = fmaxf(fmaxf(sf[qr][0][rg], sf[qr][1][rg]), fmaxf(sf[qr][2][rg], sf[qr][3][rg]));
#pragma unroll
                    for (int off = 8; off > 0; off >>= 1) mx = fmaxf(mx, __shfl_xor(mx, off));
                    float mn = fmaxf(m_i[qr][rg], mx);
                    alpha[rg] = __expf(m_i[qr][rg] - mn);
                    m_i[qr][rg] = mn;
                    rs[rg] = 0.f;
                }
#pragma unroll
                for (int nt = 0; nt < 4; ++nt)
#pragma unroll
                    for (int rg = 0; rg < 4; ++rg) {
                        float p = __expf(sf[qr][nt][rg] - m_i[qr][rg]);
                        rs[rg] += p;
                        Ps[wave][qr * 16 + quad * 4 + rg][nt * 16 + row16] = __float2bfloat16(p);
                    }
#pragma unroll
                for (int rg = 0; rg < 4; ++rg) {
#pragma unroll
                    for (int off = 8; off > 0; off >>= 1) rs[rg] += __shfl_xor(rs[rg], off);
                    l_i[qr][rg] = l_i[qr][rg] * alpha[rg] + rs[rg];
                }
#pragma unroll
                for (int dt = 0; dt < 8; ++dt)
#pragma unroll
                    for (int rg = 0; rg < 4; ++rg) oa[qr][dt][rg] *= alpha[rg];
            }
            __builtin_amdgcn_wave_barrier();   // order Ps writes before reads (same wave)
            bf16x8 pf[2][2];
#pragma unroll
            for (int qr = 0; qr < 2; ++qr) {
                pf[qr][0] = *(const bf16x8*)&Ps[wave][qr * 16 + row16][quad * 8];
                pf[qr][1] = *(const bf16x8*)&Ps[wave][qr * 16 + row16][32 + quad * 8];
            }
#pragma unroll
            for (int dt = 0; dt < 8; ++dt) {
                bf16x8 v0 = *(const bf16x8*)&Vf[s][dt * 2][lane * 8];
                bf16x8 v1 = *(const bf16x8*)&Vf[s][dt * 2 + 1][lane * 8];
#pragma unroll
                for (int qr = 0; qr < 2; ++qr) {
                    oa[qr][dt] = __builtin_amdgcn_mfma_f32_16x16x32_bf16(pf[qr][0], v0, oa[qr][dt], 0, 0, 0);
                    oa[qr][dt] = __builtin_amdgcn_mfma_f32_16x16x32_bf16(pf[qr][1], v1, oa[qr][dt], 0, 0, 0);
                }
            }
        }
        asm volatile("s_waitcnt vmcnt(0)" ::: "memory");
        __builtin_amdgcn_s_barrier();
        __builtin_amdgcn_sched_barrier(0);
    }
#pragma unroll
    for (int qr = 0; qr < 2; ++qr)
#pragma unroll
        for (int rg = 0; rg < 4; ++rg) {
            float inv = 1.0f / l_i[qr][rg];
            __hip_bfloat16* orow = qb + (size_t)(wbase + qr * 16 + quad * 4 + rg) * QKV;
#pragma unroll
            for (int dt = 0; dt < 8; ++dt)
                orow[dt * 16 + row16] = __float2bfloat16(oa[qr][dt][rg] * inv);
        }
}

extern "C" void kernel_launch(void* const* d_in, const int* in_sizes, int n_in,
                              void* d_out, int out_size, void* d_ws, size_t ws_size,
                              hipStream_t stream) {
    const float* hs = (const float*)d_in[0];
    const float* Wp = (const float*)d_in[3];
    const float* Wo = (const float*)d_in[4];
    float* out = (float*)d_out;

    const size_t SZ_PROJ = (size_t)MTOT * QKV;      // bf16 elems
    const size_t SZ_H    = (size_t)MTOT * HIDDEN;
    const size_t SZ_WP   = (size_t)QKV * HIDDEN;
    const size_t need = (SZ_PROJ + SZ_H + SZ_WP + SZ_H) * sizeof(__hip_bfloat16);  // 256 MiB

    __hip_bfloat16* proj = (__hip_bfloat16*)d_ws;

    if (ws_size >= need) {
        // [proj][hsb][Wpb][Wob]; vtg aliases the (dead-after-GEMM1) hsb region.
        __hip_bfloat16* hsb = proj + SZ_PROJ;
        __hip_bfloat16* Wpb = hsb + SZ_H;
        __hip_bfloat16* Wob = Wpb + SZ_WP;
        __hip_bfloat16* vtg = hsb;   // 33.6 MB, fits in hsb+Wpb (134 MB)

        cvt_bf16<<<dim3(SZ_H / 8 / 256), dim3(256), 0, stream>>>(hs, hsb, SZ_H / 8);
        cvt_bf16<<<dim3(SZ_WP / 8 / 256), dim3(256), 0, stream>>>(Wp, Wpb, SZ_WP / 8);
        cvt_bf16<<<dim3(SZ_H / 8 / 256), dim3(256), 0, stream>>>(Wo, Wob, SZ_H / 8);
        gemm_256<<<dim3(QKV / 256, MTOT / 256), dim3(512), 0, stream>>>(hsb, Wpb, proj, MTOT, QKV, HIDDEN, HIDDEN);
        rope_kernel<<<dim3((MTOT * 2 * NH * 64) / 256), dim3(256), 0, stream>>>(proj);
        transpose_v<<<dim3(SEQ / 64, BATCH * NH), dim3(256), 0, stream>>>(proj, vtg);
        attn_mfma<<<dim3(SEQ / 256, BATCH * NH), dim3(512), 0, stream>>>(proj, vtg);
        gemm_256<<<dim3(HIDDEN / 256, MTOT / 256), dim3(512), 0, stream>>>(proj, Wob, out, MTOT, HIDDEN, HIDDEN, QKV);
    } else {
        // proven 128-MiB fallback (round-4 path)
        __hip_bfloat16* vtg = proj + SZ_PROJ;
        gemm_bt<<<dim3(QKV / 128, MTOT / 128), dim3(256), 0, stream>>>(hs, Wp, proj, MTOT, QKV, HIDDEN, HIDDEN);
        rope_kernel<<<dim3((MTOT * 2 * NH * 64) / 256), dim3(256), 0, stream>>>(proj);
        transpose_v<<<dim3(SEQ / 64, BATCH * NH), dim3(256), 0, stream>>>(proj, vtg);
        attn_mfma<<<dim3(SEQ / 256, BATCH * NH), dim3(512), 0, stream>>>(proj, vtg);
        gemm_bt<<<dim3(HIDDEN / 128, MTOT / 128), dim3(256), 0, stream>>>(proj, Wo, out, MTOT, HIDDEN, HIDDEN, QKV);
    }
}

// Round 9
// 1105.185 us; speedup vs baseline: 1.1721x; 1.0046x over previous
//
#include <hip/hip_runtime.h>
#include <hip/hip_bf16.h>

typedef __bf16 bf16x8 __attribute__((ext_vector_type(8)));
typedef float f32x4 __attribute__((ext_vector_type(4)));

#define HIDDEN 4096
#define NH 32
#define HD 128
#define SEQ 2048
#define BATCH 2
#define MTOT 4096           // BATCH*SEQ
#define QKV 12288

// ---- async global->LDS, 16B per lane; LDS dest = wave-uniform base + lane*16 ----
__device__ __forceinline__ void async16(const void* g, void* l) {
    __builtin_amdgcn_global_load_lds(
        (const __attribute__((address_space(1))) void*)(uintptr_t)g,
        (__attribute__((address_space(3))) void*)(uint32_t)(uintptr_t)l,
        16, 0, 0);
}

// Load 8 source elements and return them as 8 packed bf16 (one uint4).
__device__ __forceinline__ uint4 ld8(const __hip_bfloat16* p) { return *(const uint4*)p; }
__device__ __forceinline__ uint4 ld8(const float* p) {
    float4 a = *(const float4*)p;
    float4 b = *(const float4*)(p + 4);
    __hip_bfloat16 t[8];
    t[0] = __float2bfloat16(a.x); t[1] = __float2bfloat16(a.y);
    t[2] = __float2bfloat16(a.z); t[3] = __float2bfloat16(a.w);
    t[4] = __float2bfloat16(b.x); t[5] = __float2bfloat16(b.y);
    t[6] = __float2bfloat16(b.z); t[7] = __float2bfloat16(b.w);
    return *(uint4*)t;
}

__device__ __forceinline__ void stc(__hip_bfloat16* C, size_t i, float v) { C[i] = __float2bfloat16(v); }
__device__ __forceinline__ void stc(float* C, size_t i, float v) { C[i] = v; }

// fp32 -> bf16 bulk convert, 8 elems/thread.
__global__ __launch_bounds__(256) void cvt_bf16(const float* __restrict__ src,
                                                __hip_bfloat16* __restrict__ dst, int n8) {
    int i = blockIdx.x * 256 + threadIdx.x;
    if (i < n8) *(uint4*)&dst[(size_t)i * 8] = ld8(&src[(size_t)i * 8]);
}

// 256x256-tile GEMM, BK=64, 2-slot LDS ring, 4-PHASE interleave per K-tile
// (m201-style T3). C[M,N] = A[M,K] @ Bt[N,K]^T, bf16 in, fp32 MFMA acc.
// 8 waves (2M x 4N), per-wave output 128x64 (acc[8][4]).
//
// Round-8 verified parts kept: BK=64 ring, issue-early staging, both-sides
// XOR swizzle (store chunk c of row r at c^(r&7); global source chunk
// pre-permuted (lane&7)^(lane>>3) -- bank conflicts measured ZERO).
//
// NEW (this round): each K-tile's compute is split into 4 phases
// (ks-half x i-half, 16 MFMA each): {ds_read subtile || stage issue ->
// s_barrier -> lgkmcnt(0) -> setprio(1) 16 MFMA setprio(0) -> s_barrier}.
// All 8 staging loads issue in phases 0-1 so the last has >=3 phases of
// flight before next tile's vmcnt(0). Phases have NO data hazards (slot
// fully landed at tile top) -- barriers are pure scheduling, correctness
// identical to round 8. Slot audit unchanged: stage targets s^1, whose
// last reads preceded this tile's top barrier.
template <typename TC>
__global__ __launch_bounds__(512) void gemm_256(const __hip_bfloat16* __restrict__ A,
                                                const __hip_bfloat16* __restrict__ Bt,
                                                TC* __restrict__ C,
                                                int M, int N, int K, int lda) {
    __shared__ __align__(16) __hip_bfloat16 As[2][256][64];   // 64 KiB
    __shared__ __align__(16) __hip_bfloat16 Bs[2][256][64];   // 64 KiB
    const int bn = blockIdx.x * 256, bm = blockIdx.y * 256;
    const int tid = threadIdx.x, wave = tid >> 6, lane = tid & 63;
    const int wm = wave >> 2, wn = wave & 3;      // 2 x 4 wave grid
    const int row16 = lane & 15, quad = lane >> 4;
    const int srow = lane >> 3;                   // 0..7: row within 8-row strip
    const int schunk = (lane & 7) ^ srow;         // pre-swizzled source chunk
    const __hip_bfloat16* Ab = A + (size_t)(bm + wave * 8 + srow) * lda + schunk * 8;
    const __hip_bfloat16* Bb = Bt + (size_t)(bn + wave * 8 + srow) * K + schunk * 8;
    const int NT = K >> 6;

    f32x4 acc[8][4] = {};

    // prologue: stage tile 0 into slot 0
    {
#pragma unroll
        for (int k = 0; k < 4; ++k) {
            async16(Ab + (size_t)(k * 64) * lda, &As[0][k * 64 + wave * 8][0]);
            async16(Bb + (size_t)(k * 64) * K,  &Bs[0][k * 64 + wave * 8][0]);
        }
    }

    for (int t = 0; t < NT; ++t) {
        const int s = t & 1, s1 = s ^ 1;
        const size_t kt1 = (size_t)(t + 1) << 6;
        const bool more = (t + 1 < NT);
        asm volatile("s_waitcnt vmcnt(0)" ::: "memory");   // own loads for tile t landed
        __builtin_amdgcn_s_barrier();                      // => everyone's landed
        __builtin_amdgcn_sched_barrier(0);
        bf16x8 bf[4];
#pragma unroll
        for (int p = 0; p < 4; ++p) {
            const int ks = p >> 1, ih = p & 1;
            const int pc = ((ks * 4 + quad) ^ (row16 & 7)) * 8;   // swizzled chunk
            bf16x8 af[4];
            if (ih == 0) {
#pragma unroll
                for (int j = 0; j < 4; ++j)
                    bf[j] = *(const bf16x8*)&Bs[s][wn * 64 + j * 16 + row16][pc];
            }
#pragma unroll
            for (int i = 0; i < 4; ++i)
                af[i] = *(const bf16x8*)&As[s][wm * 128 + (ih * 4 + i) * 16 + row16][pc];
            if (more && p == 0) {
#pragma unroll
                for (int k = 0; k < 4; ++k)
                    async16(Ab + (size_t)(k * 64) * lda + kt1, &As[s1][k * 64 + wave * 8][0]);
            }
            if (more && p == 1) {
#pragma unroll
                for (int k = 0; k < 4; ++k)
                    async16(Bb + (size_t)(k * 64) * K + kt1, &Bs[s1][k * 64 + wave * 8][0]);
            }
            __builtin_amdgcn_sched_barrier(0);             // reads+stages pinned above
            __builtin_amdgcn_s_barrier();
            asm volatile("s_waitcnt lgkmcnt(0)" ::: "memory");
            __builtin_amdgcn_sched_barrier(0);             // rule #18
            __builtin_amdgcn_s_setprio(1);
#pragma unroll
            for (int i = 0; i < 4; ++i)
#pragma unroll
                for (int j = 0; j < 4; ++j)
                    acc[ih * 4 + i][j] = __builtin_amdgcn_mfma_f32_16x16x32_bf16(af[i], bf[j], acc[ih * 4 + i][j], 0, 0, 0);
            __builtin_amdgcn_s_setprio(0);
            __builtin_amdgcn_s_barrier();
        }
    }

    const int col0 = bn + wn * 64 + row16;
    const int row0 = bm + wm * 128 + quad * 4;
#pragma unroll
    for (int i = 0; i < 8; ++i)
#pragma unroll
        for (int j = 0; j < 4; ++j)
#pragma unroll
            for (int rg = 0; rg < 4; ++rg)
                stc(C, (size_t)(row0 + i * 16 + rg) * N + col0 + j * 16, acc[i][j][rg]);
}

// Fallback GEMM (fp32 or bf16 inputs via ld8 staging). Used when ws is small.
template <typename TA, typename TB, typename TC>
__global__ __launch_bounds__(256) void gemm_bt(const TA* __restrict__ A,
                                               const TB* __restrict__ Bt,
                                               TC* __restrict__ C,
                                               int M, int N, int K, int lda) {
    __shared__ __align__(16) __hip_bfloat16 As[128][32];
    __shared__ __align__(16) __hip_bfloat16 Bs[128][32];
    const int bn = blockIdx.x * 128, bm = blockIdx.y * 128;
    const int tid = threadIdx.x, wave = tid >> 6, lane = tid & 63;
    const int wm = (wave >> 1) * 64, wn = (wave & 1) * 64;
    const int row16 = lane & 15, quad = lane >> 4;
    const int arow = tid >> 2;
    const int acol = (tid & 3) * 8;

    f32x4 acc[4][4] = {};

    for (int kt = 0; kt < K; kt += 32) {
        __syncthreads();
#pragma unroll
        for (int it = 0; it < 2; ++it) {
            int r = arow + it * 64;
            *(uint4*)&As[r][acol] = ld8(&A[(size_t)(bm + r) * lda + kt + acol]);
            *(uint4*)&Bs[r][acol] = ld8(&Bt[(size_t)(bn + r) * K + kt + acol]);
        }
        __syncthreads();
        bf16x8 af[4], bf[4];
#pragma unroll
        for (int i = 0; i < 4; ++i) af[i] = *(const bf16x8*)&As[wm + i * 16 + row16][quad * 8];
#pragma unroll
        for (int j = 0; j < 4; ++j) bf[j] = *(const bf16x8*)&Bs[wn + j * 16 + row16][quad * 8];
#pragma unroll
        for (int i = 0; i < 4; ++i)
#pragma unroll
            for (int j = 0; j < 4; ++j)
                acc[i][j] = __builtin_amdgcn_mfma_f32_16x16x32_bf16(af[i], bf[j], acc[i][j], 0, 0, 0);
    }
    const int col0 = bn + wn + row16;
    const int row0 = bm + wm + quad * 4;
#pragma unroll
    for (int i = 0; i < 4; ++i)
#pragma unroll
        for (int j = 0; j < 4; ++j)
#pragma unroll
            for (int rg = 0; rg < 4; ++rg)
                stc(C, (size_t)(row0 + i * 16 + rg) * N + col0 + j * 16, acc[i][j][rg]);
}

// In-place RoPE on the Q and K thirds of proj[MTOT][QKV]. position = row % SEQ.
// Q rows additionally pre-scaled by 1/sqrt(HD) so attn skips the score scaling.
__global__ __launch_bounds__(256) void rope_kernel(__hip_bfloat16* __restrict__ proj) {
    int t = blockIdx.x * 256 + threadIdx.x;
    int j = t & 63;
    int head = (t >> 6) & 31;
    int mat = (t >> 11) & 1;
    int row = t >> 12;
    int pos = row & (SEQ - 1);
    float invf = __expf(-(float)j * 0.14391156514261f);   // 10000^(-j/64)
    float ang = (float)pos * invf;
    float rev = ang * 0.15915494309189535f;               // range-reduce for v_sin/v_cos
    rev -= floorf(rev);
    float arad = rev * 6.283185307179586f;
    float sn = __sinf(arad);
    float cs = __cosf(arad);
    if (mat == 0) {                     // Q third: fold in 1/sqrt(128)
        sn *= 0.08838834764831845f;
        cs *= 0.08838834764831845f;
    }
    size_t base = (size_t)row * QKV + mat * HIDDEN + head * HD + j;
    float x1 = __bfloat162float(proj[base]);
    float x2 = __bfloat162float(proj[base + 64]);
    proj[base]      = __float2bfloat16(x1 * cs - x2 * sn);
    proj[base + 64] = __float2bfloat16(x2 * cs + x1 * sn);
}

// One-shot V transpose: proj V-third [b][s][h*128+d] -> vtg[(b*32+h)][d][s].
__global__ __launch_bounds__(256) void transpose_v(const __hip_bfloat16* __restrict__ proj,
                                                   __hip_bfloat16* __restrict__ vtg) {
    __shared__ __hip_bfloat16 Ls[64][132];
    const int st = blockIdx.x, bh = blockIdx.y;
    const int b = bh >> 5, h = bh & 31;
    const int s0 = st << 6;
    const int tid = threadIdx.x;
    const __hip_bfloat16* vb = proj + (size_t)b * SEQ * QKV + 2 * HIDDEN + h * HD;
    for (int i = tid; i < 1024; i += 256) {
        int r = i >> 4, c = (i & 15) << 3;
        uint4 raw = *(const uint4*)&vb[(size_t)(s0 + r) * QKV + c];
        *(uint2*)&Ls[r][c]     = make_uint2(raw.x, raw.y);
        *(uint2*)&Ls[r][c + 4] = make_uint2(raw.z, raw.w);
    }
    __syncthreads();
    __hip_bfloat16* ob = vtg + (size_t)bh * HD * SEQ + s0;
    for (int t = tid; t < 1024; t += 256) {
        int d = t >> 3, sc = (t & 7) << 3;
        __hip_bfloat16 tmp[8];
#pragma unroll
        for (int x = 0; x < 8; ++x) tmp[x] = Ls[sc + x][d];
        *(uint4*)&ob[(size_t)d * SEQ + sc] = *(uint4*)tmp;
    }
}

// MFMA flash attention, ring-staged. Block = 256 q-rows x (b,h); 8 waves x
// 32 q-rows. K/V staged via global_load_lds into fragment-ordered 1-KiB
// blocks, 2-slot ring, ONE barrier per 64-key tile (round-7/8 verified).
__global__ __launch_bounds__(512) void attn_mfma(__hip_bfloat16* __restrict__ proj,
                                                 const __hip_bfloat16* __restrict__ vtg) {
    __shared__ __align__(16) __hip_bfloat16 Kf[2][16][512];  // 32 KiB
    __shared__ __align__(16) __hip_bfloat16 Vf[2][16][512];  // 32 KiB
    __shared__ __align__(16) __hip_bfloat16 Ps[8][32][72];   // 36 KiB
    const int nwg = gridDim.x * gridDim.y;
    const int f  = blockIdx.y * gridDim.x + blockIdx.x;
    const int f2 = (f & 7) * (nwg >> 3) + (f >> 3);
    const int qt = f2 & 7;             // gridDim.x == 8
    const int bh = f2 >> 3;
    const int b = bh >> 5, h = bh & 31;
    const int q0 = qt << 8;
    const int tid = threadIdx.x, wave = tid >> 6, lane = tid & 63;
    const int row16 = lane & 15, quad = lane >> 4;

    __hip_bfloat16* qb = proj + (size_t)b * SEQ * QKV + h * HD;
    const __hip_bfloat16* kb = qb + HIDDEN;
    const __hip_bfloat16* vp = vtg + (size_t)bh * HD * SEQ;

    const int wbase = q0 + wave * 32;

    const int b0 = 2 * wave, b1 = 2 * wave + 1;
    const __hip_bfloat16* ks0 = kb + (size_t)((b0 >> 2) * 16 + row16) * QKV + (b0 & 3) * 32 + quad * 8;
    const __hip_bfloat16* ks1 = kb + (size_t)((b1 >> 2) * 16 + row16) * QKV + (b1 & 3) * 32 + quad * 8;
    const __hip_bfloat16* vs0 = vp + (size_t)((b0 >> 1) * 16 + row16) * SEQ + (b0 & 1) * 32 + quad * 8;
    const __hip_bfloat16* vs1 = vp + (size_t)((b1 >> 1) * 16 + row16) * SEQ + (b1 & 1) * 32 + quad * 8;

    auto stage = [&](int kt) {
        const int s = kt & 1;
        const int k0 = kt << 6;
        async16(ks0 + (size_t)k0 * QKV, &Kf[s][b0][0]);
        async16(ks1 + (size_t)k0 * QKV, &Kf[s][b1][0]);
        async16(vs0 + k0,               &Vf[s][b0][0]);
        async16(vs1 + k0,               &Vf[s][b1][0]);
    };

    bf16x8 qf[2][4];
#pragma unroll
    for (int qr = 0; qr < 2; ++qr) {
        const __hip_bfloat16* qrow = qb + (size_t)(wbase + qr * 16 + row16) * QKV + quad * 8;
#pragma unroll
        for (int s = 0; s < 4; ++s) qf[qr][s] = *(const bf16x8*)(qrow + s * 32);
    }

    f32x4 oa[2][8] = {};
    float m_i[2][4], l_i[2][4];
#pragma unroll
    for (int qr = 0; qr < 2; ++qr)
#pragma unroll
        for (int r = 0; r < 4; ++r) { m_i[qr][r] = -3.0e38f; l_i[qr][r] = 0.f; }

    stage(0);
    asm volatile("s_waitcnt vmcnt(0)" ::: "memory");
    __builtin_amdgcn_s_barrier();
    __builtin_amdgcn_sched_barrier(0);

    const int ktmax = 4 * qt + 3;
    for (int kt = 0; kt <= ktmax; ++kt) {
        const int s = kt & 1;
        const int k0 = kt << 6;
        if (kt < ktmax) stage(kt + 1);
        if (k0 <= wbase + 31) {          // wave-uniform active test
            f32x4 sf[2][4] = {};
#pragma unroll
            for (int nt = 0; nt < 4; ++nt) {
                bf16x8 kf[4];
#pragma unroll
                for (int ks = 0; ks < 4; ++ks)
                    kf[ks] = *(const bf16x8*)&Kf[s][nt * 4 + ks][lane * 8];
#pragma unroll
                for (int qr = 0; qr < 2; ++qr)
#pragma unroll
                    for (int ks = 0; ks < 4; ++ks)
                        sf[qr][nt] = __builtin_amdgcn_mfma_f32_16x16x32_bf16(qf[qr][ks], kf[ks], sf[qr][nt], 0, 0, 0);
            }
            if (k0 + 63 > wbase) {       // diagonal region: causal mask
#pragma unroll
                for (int qr = 0; qr < 2; ++qr)
#pragma unroll
                    for (int nt = 0; nt < 4; ++nt) {
                        int key = k0 + nt * 16 + row16;
#pragma unroll
                        for (int rg = 0; rg < 4; ++rg)
                            if (key > wbase + qr * 16 + quad * 4 + rg) sf[qr][nt][rg] = -3.0e38f;
                    }
            }
#pragma unroll
            for (int qr = 0; qr < 2; ++qr) {
                float alpha[4], rs[4];
#pragma unroll
                for (int rg = 0; rg < 4; ++rg) {
                    float mx = fmaxf(fmaxf(sf[qr][0][rg], sf[qr][1][rg]), fmaxf(sf[qr][2][rg], sf[qr][3][rg]));
#pragma unroll
                    for (int off = 8; off > 0; off >>= 1) mx = fmaxf(mx, __shfl_xor(mx, off));
                    float mn = fmaxf(m_i[qr][rg], mx);
                    alpha[rg] = __expf(m_i[qr][rg] - mn);
                    m_i[qr][rg] = mn;
                    rs[rg] = 0.f;
                }
#pragma unroll
                for (int nt = 0; nt < 4; ++nt)
#pragma unroll
                    for (int rg = 0; rg < 4; ++rg) {
                        float p = __expf(sf[qr][nt][rg] - m_i[qr][rg]);
                        rs[rg] += p;
                        Ps[wave][qr * 16 + quad * 4 + rg][nt * 16 + row16] = __float2bfloat16(p);
                    }
#pragma unroll
                for (int rg = 0; rg < 4; ++rg) {
#pragma unroll
                    for (int off = 8; off > 0; off >>= 1) rs[rg] += __shfl_xor(rs[rg], off);
                    l_i[qr][rg] = l_i[qr][rg] * alpha[rg] + rs[rg];
                }
#pragma unroll
                for (int dt = 0; dt < 8; ++dt)
#pragma unroll
                    for (int rg = 0; rg < 4; ++rg) oa[qr][dt][rg] *= alpha[rg];
            }
            __builtin_amdgcn_wave_barrier();   // order Ps writes before reads (same wave)
            bf16x8 pf[2][2];
#pragma unroll
            for (int qr = 0; qr < 2; ++qr) {
                pf[qr][0] = *(const bf16x8*)&Ps[wave][qr * 16 + row16][quad * 8];
                pf[qr][1] = *(const bf16x8*)&Ps[wave][qr * 16 + row16][32 + quad * 8];
            }
#pragma unroll
            for (int dt = 0; dt < 8; ++dt) {
                bf16x8 v0 = *(const bf16x8*)&Vf[s][dt * 2][lane * 8];
                bf16x8 v1 = *(const bf16x8*)&Vf[s][dt * 2 + 1][lane * 8];
#pragma unroll
                for (int qr = 0; qr < 2; ++qr) {
                    oa[qr][dt] = __builtin_amdgcn_mfma_f32_16x16x32_bf16(pf[qr][0], v0, oa[qr][dt], 0, 0, 0);
                    oa[qr][dt] = __builtin_amdgcn_mfma_f32_16x16x32_bf16(pf[qr][1], v1, oa[qr][dt], 0, 0, 0);
                }
            }
        }
        asm volatile("s_waitcnt vmcnt(0)" ::: "memory");
        __builtin_amdgcn_s_barrier();
        __builtin_amdgcn_sched_barrier(0);
    }
#pragma unroll
    for (int qr = 0; qr < 2; ++qr)
#pragma unroll
        for (int rg = 0; rg < 4; ++rg) {
            float inv = 1.0f / l_i[qr][rg];
            __hip_bfloat16* orow = qb + (size_t)(wbase + qr * 16 + quad * 4 + rg) * QKV;
#pragma unroll
            for (int dt = 0; dt < 8; ++dt)
                orow[dt * 16 + row16] = __float2bfloat16(oa[qr][dt][rg] * inv);
        }
}

extern "C" void kernel_launch(void* const* d_in, const int* in_sizes, int n_in,
                              void* d_out, int out_size, void* d_ws, size_t ws_size,
                              hipStream_t stream) {
    const float* hs = (const float*)d_in[0];
    const float* Wp = (const float*)d_in[3];
    const float* Wo = (const float*)d_in[4];
    float* out = (float*)d_out;

    const size_t SZ_PROJ = (size_t)MTOT * QKV;      // bf16 elems
    const size_t SZ_H    = (size_t)MTOT * HIDDEN;
    const size_t SZ_WP   = (size_t)QKV * HIDDEN;
    const size_t need = (SZ_PROJ + SZ_H + SZ_WP + SZ_H) * sizeof(__hip_bfloat16);  // 256 MiB

    __hip_bfloat16* proj = (__hip_bfloat16*)d_ws;

    if (ws_size >= need) {
        // [proj][hsb][Wpb][Wob]; vtg aliases the (dead-after-GEMM1) hsb region.
        __hip_bfloat16* hsb = proj + SZ_PROJ;
        __hip_bfloat16* Wpb = hsb + SZ_H;
        __hip_bfloat16* Wob = Wpb + SZ_WP;
        __hip_bfloat16* vtg = hsb;   // 33.6 MB, fits in hsb+Wpb (134 MB)

        cvt_bf16<<<dim3(SZ_H / 8 / 256), dim3(256), 0, stream>>>(hs, hsb, SZ_H / 8);
        cvt_bf16<<<dim3(SZ_WP / 8 / 256), dim3(256), 0, stream>>>(Wp, Wpb, SZ_WP / 8);
        cvt_bf16<<<dim3(SZ_H / 8 / 256), dim3(256), 0, stream>>>(Wo, Wob, SZ_H / 8);
        gemm_256<<<dim3(QKV / 256, MTOT / 256), dim3(512), 0, stream>>>(hsb, Wpb, proj, MTOT, QKV, HIDDEN, HIDDEN);
        rope_kernel<<<dim3((MTOT * 2 * NH * 64) / 256), dim3(256), 0, stream>>>(proj);
        transpose_v<<<dim3(SEQ / 64, BATCH * NH), dim3(256), 0, stream>>>(proj, vtg);
        attn_mfma<<<dim3(SEQ / 256, BATCH * NH), dim3(512), 0, stream>>>(proj, vtg);
        gemm_256<<<dim3(HIDDEN / 256, MTOT / 256), dim3(512), 0, stream>>>(proj, Wob, out, MTOT, HIDDEN, HIDDEN, QKV);
    } else {
        // proven 128-MiB fallback (round-4 path)
        __hip_bfloat16* vtg = proj + SZ_PROJ;
        gemm_bt<<<dim3(QKV / 128, MTOT / 128), dim3(256), 0, stream>>>(hs, Wp, proj, MTOT, QKV, HIDDEN, HIDDEN);
        rope_kernel<<<dim3((MTOT * 2 * NH * 64) / 256), dim3(256), 0, stream>>>(proj);
        transpose_v<<<dim3(SEQ / 64, BATCH * NH), dim3(256), 0, stream>>>(proj, vtg);
        attn_mfma<<<dim3(SEQ / 256, BATCH * NH), dim3(512), 0, stream>>>(proj, vtg);
        gemm_bt<<<dim3(HIDDEN / 128, MTOT / 128), dim3(256), 0, stream>>>(proj, Wo, out, MTOT, HIDDEN, HIDDEN, QKV);
    }
}

// Round 10
// 1100.406 us; speedup vs baseline: 1.1772x; 1.0043x over previous
//
#include <hip/hip_runtime.h>
#include <hip/hip_bf16.h>

typedef __bf16 bf16x8 __attribute__((ext_vector_type(8)));
typedef float f32x4 __attribute__((ext_vector_type(4)));

#define HIDDEN 4096
#define NH 32
#define HD 128
#define SEQ 2048
#define BATCH 2
#define MTOT 4096           // BATCH*SEQ
#define QKV 12288

// ---- async global->LDS, 16B per lane; LDS dest = wave-uniform base + lane*16 ----
__device__ __forceinline__ void async16(const void* g, void* l) {
    __builtin_amdgcn_global_load_lds(
        (const __attribute__((address_space(1))) void*)(uintptr_t)g,
        (__attribute__((address_space(3))) void*)(uint32_t)(uintptr_t)l,
        16, 0, 0);
}

// Load 8 source elements and return them as 8 packed bf16 (one uint4).
__device__ __forceinline__ uint4 ld8(const __hip_bfloat16* p) { return *(const uint4*)p; }
__device__ __forceinline__ uint4 ld8(const float* p) {
    float4 a = *(const float4*)p;
    float4 b = *(const float4*)(p + 4);
    __hip_bfloat16 t[8];
    t[0] = __float2bfloat16(a.x); t[1] = __float2bfloat16(a.y);
    t[2] = __float2bfloat16(a.z); t[3] = __float2bfloat16(a.w);
    t[4] = __float2bfloat16(b.x); t[5] = __float2bfloat16(b.y);
    t[6] = __float2bfloat16(b.z); t[7] = __float2bfloat16(b.w);
    return *(uint4*)t;
}

__device__ __forceinline__ void stc(__hip_bfloat16* C, size_t i, float v) { C[i] = __float2bfloat16(v); }
__device__ __forceinline__ void stc(float* C, size_t i, float v) { C[i] = v; }

// fp32 -> bf16 bulk convert, 8 elems/thread.
__global__ __launch_bounds__(256) void cvt_bf16(const float* __restrict__ src,
                                                __hip_bfloat16* __restrict__ dst, int n8) {
    int i = blockIdx.x * 256 + threadIdx.x;
    if (i < n8) *(uint4*)&dst[(size_t)i * 8] = ld8(&src[(size_t)i * 8]);
}

// 256x256-tile GEMM, BK=64, 2-slot ring, 4-phase interleave with COUNTED
// vmcnt (T3+T4+T5+T2). C[M,N] = A[M,K] @ Bt[N,K]^T, bf16 in, fp32 acc.
// 8 waves (2M x 4N), per-wave output 128x64 (acc[8][4]).
//
// r9 lesson (matches m218): 8-phase-with-drain0 == 1-phase. The gain IS the
// counted vmcnt: vmcnt(0) eats the HBM queue tail every tile (256 CUs issue
// stage bursts semi-synchronized -> tail latency >> 900cy); counted waits
// only require loads issued >=2 phases (~1800cy) earlier.
//
// Stage units (per wave, each = 1 async16 = 64 rows x all 64 cols across the
// block): SA(k)/SB(k), k=0..3 -> rows [k*64,k*64+64).
// Need-before (from ds_read pattern): phase0 needs {B0-3, A0, A2};
// phase1 needs {A1, A3}; phases 2,3 reuse (stages hold both K-halves).
// Issue during tile t (for t+1): p0: SB0-3; p1: SA0,SA2; p2: SA1,SA3.
// Counted waits: p0: vmcnt(4)  (leaves the 4 just-issued SBs; drains t's
//   A1,A3 -- needed at p1, two barriers later);
// p3: vmcnt(2)  (leaves t+1's A1,A3; drains t+1's B0-3/A0,A2 -- needed at
//   next tile's p0, all issued >=2 phases earlier). NEVER 0 in main loop.
// Slot audit: t+1 writes slot s^1, whose last reads (t-1 p3) are closed by
// that phase's end barrier < t's p0. Swizzle both-sides as r8 (conflicts=0).
template <typename TC>
__global__ __launch_bounds__(512) void gemm_256(const __hip_bfloat16* __restrict__ A,
                                                const __hip_bfloat16* __restrict__ Bt,
                                                TC* __restrict__ C,
                                                int M, int N, int K, int lda) {
    __shared__ __align__(16) __hip_bfloat16 As[2][256][64];   // 64 KiB
    __shared__ __align__(16) __hip_bfloat16 Bs[2][256][64];   // 64 KiB
    const int bn = blockIdx.x * 256, bm = blockIdx.y * 256;
    const int tid = threadIdx.x, wave = tid >> 6, lane = tid & 63;
    const int wm = wave >> 2, wn = wave & 3;      // 2 x 4 wave grid
    const int row16 = lane & 15, quad = lane >> 4;
    const int srow = lane >> 3;                   // 0..7: row within 8-row strip
    const int schunk = (lane & 7) ^ srow;         // pre-swizzled source chunk
    const __hip_bfloat16* Ab = A + (size_t)(bm + wave * 8 + srow) * lda + schunk * 8;
    const __hip_bfloat16* Bb = Bt + (size_t)(bn + wave * 8 + srow) * K + schunk * 8;
    const int NT = K >> 6;

    f32x4 acc[8][4] = {};

    auto SA = [&](int k, int t) {
        async16(Ab + (size_t)(k * 64) * lda + ((size_t)t << 6), &As[t & 1][k * 64 + wave * 8][0]);
    };
    auto SB = [&](int k, int t) {
        async16(Bb + (size_t)(k * 64) * K + ((size_t)t << 6), &Bs[t & 1][k * 64 + wave * 8][0]);
    };

    // prologue: full tile 0, drained once
    SB(0, 0); SB(1, 0); SB(2, 0); SB(3, 0);
    SA(0, 0); SA(1, 0); SA(2, 0); SA(3, 0);
    asm volatile("s_waitcnt vmcnt(0)" ::: "memory");
    __builtin_amdgcn_s_barrier();

    for (int t = 0; t < NT; ++t) {
        const int s = t & 1;
        const bool more = (t + 1 < NT);
        bf16x8 bf[4];
#pragma unroll
        for (int p = 0; p < 4; ++p) {
            const int ks = p >> 1, ih = p & 1;
            const int pc = ((ks * 4 + quad) ^ (row16 & 7)) * 8;   // swizzled chunk
            bf16x8 af[4];
            if (ih == 0) {
#pragma unroll
                for (int j = 0; j < 4; ++j)
                    bf[j] = *(const bf16x8*)&Bs[s][wn * 64 + j * 16 + row16][pc];
            }
#pragma unroll
            for (int i = 0; i < 4; ++i)
                af[i] = *(const bf16x8*)&As[s][wm * 128 + (ih * 4 + i) * 16 + row16][pc];
            // staging + counted-vmcnt schedule (see header comment)
            if (p == 0) {
                if (more) {
                    SB(0, t + 1); SB(1, t + 1); SB(2, t + 1); SB(3, t + 1);
                    asm volatile("s_waitcnt vmcnt(4)" ::: "memory");
                } else {
                    asm volatile("s_waitcnt vmcnt(0)" ::: "memory");
                }
            } else if (p == 1) {
                if (more) { SA(0, t + 1); SA(2, t + 1); }
            } else if (p == 2) {
                if (more) { SA(1, t + 1); SA(3, t + 1); }
            } else {            // p == 3
                if (more) asm volatile("s_waitcnt vmcnt(2)" ::: "memory");
            }
            __builtin_amdgcn_s_barrier();
            asm volatile("s_waitcnt lgkmcnt(0)" ::: "memory");
            __builtin_amdgcn_sched_barrier(0);             // rule #18
            __builtin_amdgcn_s_setprio(1);
#pragma unroll
            for (int i = 0; i < 4; ++i)
#pragma unroll
                for (int j = 0; j < 4; ++j)
                    acc[ih * 4 + i][j] = __builtin_amdgcn_mfma_f32_16x16x32_bf16(af[i], bf[j], acc[ih * 4 + i][j], 0, 0, 0);
            __builtin_amdgcn_s_setprio(0);
            __builtin_amdgcn_s_barrier();
        }
    }

    const int col0 = bn + wn * 64 + row16;
    const int row0 = bm + wm * 128 + quad * 4;
#pragma unroll
    for (int i = 0; i < 8; ++i)
#pragma unroll
        for (int j = 0; j < 4; ++j)
#pragma unroll
            for (int rg = 0; rg < 4; ++rg)
                stc(C, (size_t)(row0 + i * 16 + rg) * N + col0 + j * 16, acc[i][j][rg]);
}

// Fallback GEMM (fp32 or bf16 inputs via ld8 staging). Used when ws is small.
template <typename TA, typename TB, typename TC>
__global__ __launch_bounds__(256) void gemm_bt(const TA* __restrict__ A,
                                               const TB* __restrict__ Bt,
                                               TC* __restrict__ C,
                                               int M, int N, int K, int lda) {
    __shared__ __align__(16) __hip_bfloat16 As[128][32];
    __shared__ __align__(16) __hip_bfloat16 Bs[128][32];
    const int bn = blockIdx.x * 128, bm = blockIdx.y * 128;
    const int tid = threadIdx.x, wave = tid >> 6, lane = tid & 63;
    const int wm = (wave >> 1) * 64, wn = (wave & 1) * 64;
    const int row16 = lane & 15, quad = lane >> 4;
    const int arow = tid >> 2;
    const int acol = (tid & 3) * 8;

    f32x4 acc[4][4] = {};

    for (int kt = 0; kt < K; kt += 32) {
        __syncthreads();
#pragma unroll
        for (int it = 0; it < 2; ++it) {
            int r = arow + it * 64;
            *(uint4*)&As[r][acol] = ld8(&A[(size_t)(bm + r) * lda + kt + acol]);
            *(uint4*)&Bs[r][acol] = ld8(&Bt[(size_t)(bn + r) * K + kt + acol]);
        }
        __syncthreads();
        bf16x8 af[4], bf[4];
#pragma unroll
        for (int i = 0; i < 4; ++i) af[i] = *(const bf16x8*)&As[wm + i * 16 + row16][quad * 8];
#pragma unroll
        for (int j = 0; j < 4; ++j) bf[j] = *(const bf16x8*)&Bs[wn + j * 16 + row16][quad * 8];
#pragma unroll
        for (int i = 0; i < 4; ++i)
#pragma unroll
            for (int j = 0; j < 4; ++j)
                acc[i][j] = __builtin_amdgcn_mfma_f32_16x16x32_bf16(af[i], bf[j], acc[i][j], 0, 0, 0);
    }
    const int col0 = bn + wn + row16;
    const int row0 = bm + wm + quad * 4;
#pragma unroll
    for (int i = 0; i < 4; ++i)
#pragma unroll
        for (int j = 0; j < 4; ++j)
#pragma unroll
            for (int rg = 0; rg < 4; ++rg)
                stc(C, (size_t)(row0 + i * 16 + rg) * N + col0 + j * 16, acc[i][j][rg]);
}

// In-place RoPE on the Q and K thirds of proj[MTOT][QKV]. position = row % SEQ.
// Q rows additionally pre-scaled by 1/sqrt(HD) so attn skips the score scaling.
__global__ __launch_bounds__(256) void rope_kernel(__hip_bfloat16* __restrict__ proj) {
    int t = blockIdx.x * 256 + threadIdx.x;
    int j = t & 63;
    int head = (t >> 6) & 31;
    int mat = (t >> 11) & 1;
    int row = t >> 12;
    int pos = row & (SEQ - 1);
    float invf = __expf(-(float)j * 0.14391156514261f);   // 10000^(-j/64)
    float ang = (float)pos * invf;
    float rev = ang * 0.15915494309189535f;               // range-reduce for v_sin/v_cos
    rev -= floorf(rev);
    float arad = rev * 6.283185307179586f;
    float sn = __sinf(arad);
    float cs = __cosf(arad);
    if (mat == 0) {                     // Q third: fold in 1/sqrt(128)
        sn *= 0.08838834764831845f;
        cs *= 0.08838834764831845f;
    }
    size_t base = (size_t)row * QKV + mat * HIDDEN + head * HD + j;
    float x1 = __bfloat162float(proj[base]);
    float x2 = __bfloat162float(proj[base + 64]);
    proj[base]      = __float2bfloat16(x1 * cs - x2 * sn);
    proj[base + 64] = __float2bfloat16(x2 * cs + x1 * sn);
}

// One-shot V transpose: proj V-third [b][s][h*128+d] -> vtg[(b*32+h)][d][s].
__global__ __launch_bounds__(256) void transpose_v(const __hip_bfloat16* __restrict__ proj,
                                                   __hip_bfloat16* __restrict__ vtg) {
    __shared__ __hip_bfloat16 Ls[64][132];
    const int st = blockIdx.x, bh = blockIdx.y;
    const int b = bh >> 5, h = bh & 31;
    const int s0 = st << 6;
    const int tid = threadIdx.x;
    const __hip_bfloat16* vb = proj + (size_t)b * SEQ * QKV + 2 * HIDDEN + h * HD;
    for (int i = tid; i < 1024; i += 256) {
        int r = i >> 4, c = (i & 15) << 3;
        uint4 raw = *(const uint4*)&vb[(size_t)(s0 + r) * QKV + c];
        *(uint2*)&Ls[r][c]     = make_uint2(raw.x, raw.y);
        *(uint2*)&Ls[r][c + 4] = make_uint2(raw.z, raw.w);
    }
    __syncthreads();
    __hip_bfloat16* ob = vtg + (size_t)bh * HD * SEQ + s0;
    for (int t = tid; t < 1024; t += 256) {
        int d = t >> 3, sc = (t & 7) << 3;
        __hip_bfloat16 tmp[8];
#pragma unroll
        for (int x = 0; x < 8; ++x) tmp[x] = Ls[sc + x][d];
        *(uint4*)&ob[(size_t)d * SEQ + sc] = *(uint4*)tmp;
    }
}

// MFMA flash attention, ring-staged. Block = 256 q-rows x (b,h); 8 waves x
// 32 q-rows. K/V staged via global_load_lds into fragment-ordered 1-KiB
// blocks, 2-slot ring, ONE barrier per 64-key tile (round-7/8 verified).
__global__ __launch_bounds__(512) void attn_mfma(__hip_bfloat16* __restrict__ proj,
                                                 const __hip_bfloat16* __restrict__ vtg) {
    __shared__ __align__(16) __hip_bfloat16 Kf[2][16][512];  // 32 KiB
    __shared__ __align__(16) __hip_bfloat16 Vf[2][16][512];  // 32 KiB
    __shared__ __align__(16) __hip_bfloat16 Ps[8][32][72];   // 36 KiB
    const int nwg = gridDim.x * gridDim.y;
    const int f  = blockIdx.y * gridDim.x + blockIdx.x;
    const int f2 = (f & 7) * (nwg >> 3) + (f >> 3);
    const int qt = f2 & 7;             // gridDim.x == 8
    const int bh = f2 >> 3;
    const int b = bh >> 5, h = bh & 31;
    const int q0 = qt << 8;
    const int tid = threadIdx.x, wave = tid >> 6, lane = tid & 63;
    const int row16 = lane & 15, quad = lane >> 4;

    __hip_bfloat16* qb = proj + (size_t)b * SEQ * QKV + h * HD;
    const __hip_bfloat16* kb = qb + HIDDEN;
    const __hip_bfloat16* vp = vtg + (size_t)bh * HD * SEQ;

    const int wbase = q0 + wave * 32;

    const int b0 = 2 * wave, b1 = 2 * wave + 1;
    const __hip_bfloat16* ks0 = kb + (size_t)((b0 >> 2) * 16 + row16) * QKV + (b0 & 3) * 32 + quad * 8;
    const __hip_bfloat16* ks1 = kb + (size_t)((b1 >> 2) * 16 + row16) * QKV + (b1 & 3) * 32 + quad * 8;
    const __hip_bfloat16* vs0 = vp + (size_t)((b0 >> 1) * 16 + row16) * SEQ + (b0 & 1) * 32 + quad * 8;
    const __hip_bfloat16* vs1 = vp + (size_t)((b1 >> 1) * 16 + row16) * SEQ + (b1 & 1) * 32 + quad * 8;

    auto stage = [&](int kt) {
        const int s = kt & 1;
        const int k0 = kt << 6;
        async16(ks0 + (size_t)k0 * QKV, &Kf[s][b0][0]);
        async16(ks1 + (size_t)k0 * QKV, &Kf[s][b1][0]);
        async16(vs0 + k0,               &Vf[s][b0][0]);
        async16(vs1 + k0,               &Vf[s][b1][0]);
    };

    bf16x8 qf[2][4];
#pragma unroll
    for (int qr = 0; qr < 2; ++qr) {
        const __hip_bfloat16* qrow = qb + (size_t)(wbase + qr * 16 + row16) * QKV + quad * 8;
#pragma unroll
        for (int s = 0; s < 4; ++s) qf[qr][s] = *(const bf16x8*)(qrow + s * 32);
    }

    f32x4 oa[2][8] = {};
    float m_i[2][4], l_i[2][4];
#pragma unroll
    for (int qr = 0; qr < 2; ++qr)
#pragma unroll
        for (int r = 0; r < 4; ++r) { m_i[qr][r] = -3.0e38f; l_i[qr][r] = 0.f; }

    stage(0);
    asm volatile("s_waitcnt vmcnt(0)" ::: "memory");
    __builtin_amdgcn_s_barrier();
    __builtin_amdgcn_sched_barrier(0);

    const int ktmax = 4 * qt + 3;
    for (int kt = 0; kt <= ktmax; ++kt) {
        const int s = kt & 1;
        const int k0 = kt << 6;
        if (kt < ktmax) stage(kt + 1);
        if (k0 <= wbase + 31) {          // wave-uniform active test
            f32x4 sf[2][4] = {};
#pragma unroll
            for (int nt = 0; nt < 4; ++nt) {
                bf16x8 kf[4];
#pragma unroll
                for (int ks = 0; ks < 4; ++ks)
                    kf[ks] = *(const bf16x8*)&Kf[s][nt * 4 + ks][lane * 8];
#pragma unroll
                for (int qr = 0; qr < 2; ++qr)
#pragma unroll
                    for (int ks = 0; ks < 4; ++ks)
                        sf[qr][nt] = __builtin_amdgcn_mfma_f32_16x16x32_bf16(qf[qr][ks], kf[ks], sf[qr][nt], 0, 0, 0);
            }
            if (k0 + 63 > wbase) {       // diagonal region: causal mask
#pragma unroll
                for (int qr = 0; qr < 2; ++qr)
#pragma unroll
                    for (int nt = 0; nt < 4; ++nt) {
                        int key = k0 + nt * 16 + row16;
#pragma unroll
                        for (int rg = 0; rg < 4; ++rg)
                            if (key > wbase + qr * 16 + quad * 4 + rg) sf[qr][nt][rg] = -3.0e38f;
                    }
            }
#pragma unroll
            for (int qr = 0; qr < 2; ++qr) {
                float alpha[4], rs[4];
#pragma unroll
                for (int rg = 0; rg < 4; ++rg) {
                    float mx = fmaxf(fmaxf(sf[qr][0][rg], sf[qr][1][rg]), fmaxf(sf[qr][2][rg], sf[qr][3][rg]));
#pragma unroll
                    for (int off = 8; off > 0; off >>= 1) mx = fmaxf(mx, __shfl_xor(mx, off));
                    float mn = fmaxf(m_i[qr][rg], mx);
                    alpha[rg] = __expf(m_i[qr][rg] - mn);
                    m_i[qr][rg] = mn;
                    rs[rg] = 0.f;
                }
#pragma unroll
                for (int nt = 0; nt < 4; ++nt)
#pragma unroll
                    for (int rg = 0; rg < 4; ++rg) {
                        float p = __expf(sf[qr][nt][rg] - m_i[qr][rg]);
                        rs[rg] += p;
                        Ps[wave][qr * 16 + quad * 4 + rg][nt * 16 + row16] = __float2bfloat16(p);
                    }
#pragma unroll
                for (int rg = 0; rg < 4; ++rg) {
#pragma unroll
                    for (int off = 8; off > 0; off >>= 1) rs[rg] += __shfl_xor(rs[rg], off);
                    l_i[qr][rg] = l_i[qr][rg] * alpha[rg] + rs[rg];
                }
#pragma unroll
                for (int dt = 0; dt < 8; ++dt)
#pragma unroll
                    for (int rg = 0; rg < 4; ++rg) oa[qr][dt][rg] *= alpha[rg];
            }
            __builtin_amdgcn_wave_barrier();   // order Ps writes before reads (same wave)
            bf16x8 pf[2][2];
#pragma unroll
            for (int qr = 0; qr < 2; ++qr) {
                pf[qr][0] = *(const bf16x8*)&Ps[wave][qr * 16 + row16][quad * 8];
                pf[qr][1] = *(const bf16x8*)&Ps[wave][qr * 16 + row16][32 + quad * 8];
            }
#pragma unroll
            for (int dt = 0; dt < 8; ++dt) {
                bf16x8 v0 = *(const bf16x8*)&Vf[s][dt * 2][lane * 8];
                bf16x8 v1 = *(const bf16x8*)&Vf[s][dt * 2 + 1][lane * 8];
#pragma unroll
                for (int qr = 0; qr < 2; ++qr) {
                    oa[qr][dt] = __builtin_amdgcn_mfma_f32_16x16x32_bf16(pf[qr][0], v0, oa[qr][dt], 0, 0, 0);
                    oa[qr][dt] = __builtin_amdgcn_mfma_f32_16x16x32_bf16(pf[qr][1], v1, oa[qr][dt], 0, 0, 0);
                }
            }
        }
        asm volatile("s_waitcnt vmcnt(0)" ::: "memory");
        __builtin_amdgcn_s_barrier();
        __builtin_amdgcn_sched_barrier(0);
    }
#pragma unroll
    for (int qr = 0; qr < 2; ++qr)
#pragma unroll
        for (int rg = 0; rg < 4; ++rg) {
            float inv = 1.0f / l_i[qr][rg];
            __hip_bfloat16* orow = qb + (size_t)(wbase + qr * 16 + quad * 4 + rg) * QKV;
#pragma unroll
            for (int dt = 0; dt < 8; ++dt)
                orow[dt * 16 + row16] = __float2bfloat16(oa[qr][dt][rg] * inv);
        }
}

extern "C" void kernel_launch(void* const* d_in, const int* in_sizes, int n_in,
                              void* d_out, int out_size, void* d_ws, size_t ws_size,
                              hipStream_t stream) {
    const float* hs = (const float*)d_in[0];
    const float* Wp = (const float*)d_in[3];
    const float* Wo = (const float*)d_in[4];
    float* out = (float*)d_out;

    const size_t SZ_PROJ = (size_t)MTOT * QKV;      // bf16 elems
    const size_t SZ_H    = (size_t)MTOT * HIDDEN;
    const size_t SZ_WP   = (size_t)QKV * HIDDEN;
    const size_t need = (SZ_PROJ + SZ_H + SZ_WP + SZ_H) * sizeof(__hip_bfloat16);  // 256 MiB

    __hip_bfloat16* proj = (__hip_bfloat16*)d_ws;

    if (ws_size >= need) {
        // [proj][hsb][Wpb][Wob]; vtg aliases the (dead-after-GEMM1) hsb region.
        __hip_bfloat16* hsb = proj + SZ_PROJ;
        __hip_bfloat16* Wpb = hsb + SZ_H;
        __hip_bfloat16* Wob = Wpb + SZ_WP;
        __hip_bfloat16* vtg = hsb;   // 33.6 MB, fits in hsb+Wpb (134 MB)

        cvt_bf16<<<dim3(SZ_H / 8 / 256), dim3(256), 0, stream>>>(hs, hsb, SZ_H / 8);
        cvt_bf16<<<dim3(SZ_WP / 8 / 256), dim3(256), 0, stream>>>(Wp, Wpb, SZ_WP / 8);
        cvt_bf16<<<dim3(SZ_H / 8 / 256), dim3(256), 0, stream>>>(Wo, Wob, SZ_H / 8);
        gemm_256<<<dim3(QKV / 256, MTOT / 256), dim3(512), 0, stream>>>(hsb, Wpb, proj, MTOT, QKV, HIDDEN, HIDDEN);
        rope_kernel<<<dim3((MTOT * 2 * NH * 64) / 256), dim3(256), 0, stream>>>(proj);
        transpose_v<<<dim3(SEQ / 64, BATCH * NH), dim3(256), 0, stream>>>(proj, vtg);
        attn_mfma<<<dim3(SEQ / 256, BATCH * NH), dim3(512), 0, stream>>>(proj, vtg);
        gemm_256<<<dim3(HIDDEN / 256, MTOT / 256), dim3(512), 0, stream>>>(proj, Wob, out, MTOT, HIDDEN, HIDDEN, QKV);
    } else {
        // proven 128-MiB fallback (round-4 path)
        __hip_bfloat16* vtg = proj + SZ_PROJ;
        gemm_bt<<<dim3(QKV / 128, MTOT / 128), dim3(256), 0, stream>>>(hs, Wp, proj, MTOT, QKV, HIDDEN, HIDDEN);
        rope_kernel<<<dim3((MTOT * 2 * NH * 64) / 256), dim3(256), 0, stream>>>(proj);
        transpose_v<<<dim3(SEQ / 64, BATCH * NH), dim3(256), 0, stream>>>(proj, vtg);
        attn_mfma<<<dim3(SEQ / 256, BATCH * NH), dim3(512), 0, stream>>>(proj, vtg);
        gemm_bt<<<dim3(HIDDEN / 128, MTOT / 128), dim3(256), 0, stream>>>(proj, Wo, out, MTOT, HIDDEN, HIDDEN, QKV);
    }
}